// Round 3
// baseline (2205.301 us; speedup 1.0000x reference)
//
#include <hip/hip_runtime.h>
#include <math.h>

#define TPB 256
static constexpr int BTT = 192;    // B*T
static constexpr int NN  = 512;    // nodes
static constexpr int DD  = 128;    // feature dim
static constexpr float SCALE = 0.25f; // 1/sqrt(16)
static constexpr float LNEPS = 1e-5f;

// ---------------- elementwise add (chunk) ----------------
__global__ void k_add(const float* __restrict__ x, const float* __restrict__ g,
                      float* __restrict__ y, int n4) {
  int i = blockIdx.x * blockDim.x + threadIdx.x;
  if (i < n4) {
    const float4* xa = (const float4*)x;
    const float4* ga = (const float4*)g;
    float4 a = xa[i], b = ga[i];
    ((float4*)y)[i] = make_float4(a.x + b.x, a.y + b.y, a.z + b.z, a.w + b.w);
  }
}

// ---------------- shared GEMM micro-kernel pieces ----------------
// tile: 128 rows x 128 cols, K in chunks of 32, 256 threads, 8x8 microtile.
// LDS rows padded to 132 floats. A staged transposed: As[k][r].
// per-thread columns: {c0a..c0a+3} and {c0a+64..c0a+67}, c0a = tc*4.

__device__ __forceinline__ void stage_straight(float (*Bs)[132], const float* __restrict__ src,
                                               int ld, int tid) {
  #pragma unroll
  for (int u = tid; u < 1024; u += TPB) {
    int kk = u >> 5, c4 = (u & 31) << 2;
    *(float4*)&Bs[kk][c4] = *(const float4*)(src + (long)kk * ld + c4);
  }
}

__device__ __forceinline__ void stage_transposed(float (*As)[132], const float* __restrict__ src,
                                                 int ld, int tid) {
  #pragma unroll
  for (int u = tid; u < 1024; u += TPB) {
    int r = u >> 3, k4 = (u & 7) << 2;
    float4 v = *(const float4*)(src + (long)r * ld + k4);
    As[k4 + 0][r] = v.x; As[k4 + 1][r] = v.y; As[k4 + 2][r] = v.z; As[k4 + 3][r] = v.w;
  }
}

__device__ __forceinline__ void mt_compute(const float (*As)[132], const float (*Bs)[132],
                                           int r0, int c0a, float acc[8][8]) {
  #pragma unroll
  for (int kk = 0; kk < 32; ++kk) {
    float a[8], b[8];
    *(float4*)&a[0] = *(const float4*)&As[kk][r0];
    *(float4*)&a[4] = *(const float4*)&As[kk][r0 + 4];
    *(float4*)&b[0] = *(const float4*)&Bs[kk][c0a];
    *(float4*)&b[4] = *(const float4*)&Bs[kk][c0a + 64];
    #pragma unroll
    for (int i = 0; i < 8; ++i)
      #pragma unroll
      for (int j = 0; j < 8; ++j)
        acc[i][j] = fmaf(a[i], b[j], acc[i][j]);
  }
}

// ---------------- GEMM + bias: C[M,128] = A[M,128]@W[128,128]+b ----------------
__global__ void k_gemm_bias(const float* __restrict__ A, const float* __restrict__ W,
                            const float* __restrict__ bias, float* __restrict__ C) {
  __shared__ float As[32][132];
  __shared__ float Bs[32][132];
  const int tid = threadIdx.x;
  const int tr = tid >> 4, tc = tid & 15;
  const int r0 = tr * 8, c0a = tc * 4;
  const long rowblk = (long)blockIdx.x * 128;
  float acc[8][8] = {};
  for (int k0 = 0; k0 < 128; k0 += 32) {
    stage_transposed(As, A + rowblk * 128 + k0, 128, tid);
    stage_straight(Bs, W + (long)k0 * 128, 128, tid);
    __syncthreads();
    mt_compute(As, Bs, r0, c0a, acc);
    __syncthreads();
  }
  float4 blo = *(const float4*)(bias + c0a);
  float4 bhi = *(const float4*)(bias + c0a + 64);
  #pragma unroll
  for (int i = 0; i < 8; ++i) {
    float* crow = C + (rowblk + r0 + i) * 128;
    *(float4*)(crow + c0a) = make_float4(acc[i][0] + blo.x, acc[i][1] + blo.y,
                                         acc[i][2] + blo.z, acc[i][3] + blo.w);
    *(float4*)(crow + c0a + 64) = make_float4(acc[i][4] + bhi.x, acc[i][5] + bhi.y,
                                              acc[i][6] + bhi.z, acc[i][7] + bhi.w);
  }
}

// ---------------- scores: S[btc][n][m] = Q[btc][n]·K[btc][m] * 0.25 ----------------
__global__ void k_scores(const float* __restrict__ Q, const float* __restrict__ K,
                         float* __restrict__ S) {
  int blk = blockIdx.x;            // btc*16 + rt*4 + ct
  int btc = blk >> 4, rt = (blk >> 2) & 3, ct = blk & 3;
  const float* Qb = Q + (long)btc * NN * DD;
  const float* Kb = K + (long)btc * NN * DD;
  float* Sb = S + (long)btc * NN * NN;
  int n0 = rt * 128, m0 = ct * 128;
  __shared__ float As[32][132];
  __shared__ float Bs[32][132];
  const int tid = threadIdx.x;
  const int tr = tid >> 4, tc = tid & 15;
  const int r0 = tr * 8, c0a = tc * 4;
  float acc[8][8] = {};
  for (int k0 = 0; k0 < 128; k0 += 32) {
    stage_transposed(As, Qb + (long)n0 * 128 + k0, 128, tid);
    stage_transposed(Bs, Kb + (long)m0 * 128 + k0, 128, tid);  // K^T
    __syncthreads();
    mt_compute(As, Bs, r0, c0a, acc);
    __syncthreads();
  }
  #pragma unroll
  for (int i = 0; i < 8; ++i) {
    float* srow = Sb + (long)(n0 + r0 + i) * NN + m0;
    *(float4*)(srow + c0a) = make_float4(acc[i][0] * SCALE, acc[i][1] * SCALE,
                                         acc[i][2] * SCALE, acc[i][3] * SCALE);
    *(float4*)(srow + c0a + 64) = make_float4(acc[i][4] * SCALE, acc[i][5] * SCALE,
                                              acc[i][6] * SCALE, acc[i][7] * SCALE);
  }
}

// ---------------- row LSE over 512 ----------------
__global__ void k_lse(const float* __restrict__ S, float* __restrict__ lse) {
  int w = threadIdx.x >> 6, lane = threadIdx.x & 63;
  long row = (long)blockIdx.x * 4 + w;
  const float4* p = (const float4*)(S + row * NN);
  float4 a = p[lane], b = p[lane + 64];
  float m = fmaxf(fmaxf(fmaxf(a.x, a.y), fmaxf(a.z, a.w)),
                  fmaxf(fmaxf(b.x, b.y), fmaxf(b.z, b.w)));
  #pragma unroll
  for (int d = 1; d < 64; d <<= 1) m = fmaxf(m, __shfl_xor(m, d));
  float s = expf(a.x - m) + expf(a.y - m) + expf(a.z - m) + expf(a.w - m)
          + expf(b.x - m) + expf(b.y - m) + expf(b.z - m) + expf(b.w - m);
  #pragma unroll
  for (int d = 1; d < 64; d <<= 1) s += __shfl_xor(s, d);
  if (lane == 0) lse[row] = m + logf(s);
}

// ---------------- column argmax: cp[btc][m] = argmax_n (S[n][m] - lse[n]) ----------------
__global__ void k_colargmax(const float* __restrict__ S, const float* __restrict__ lse,
                            int* __restrict__ cp) {
  int btc = blockIdx.x >> 1;
  int col = ((blockIdx.x & 1) << 8) + threadIdx.x;
  const float* Sb = S + (long)btc * NN * NN;
  const float* lb = lse + btc * NN;
  float best = -1e30f;
  int bi = 0;
  for (int n = 0; n < NN; ++n) {
    float v = Sb[(long)n * NN + col] - lb[n];
    if (v > best) { best = v; bi = n; }    // strict > keeps first index (jnp.argmax)
  }
  cp[btc * NN + col] = bi;
}

// ---------------- PV: attended = exp(S - lse) @ V ----------------
__global__ void k_pv(const float* __restrict__ S, const float* __restrict__ lse,
                     const float* __restrict__ V, float* __restrict__ att) {
  int blk = blockIdx.x;         // btc*4 + rt
  int btc = blk >> 2, rt = blk & 3;
  int n0 = rt * 128;
  const float* Sb = S + (long)btc * NN * NN;
  const float* lb = lse + btc * NN + n0;
  const float* Vb = V + (long)btc * NN * DD;
  __shared__ float As[32][132];
  __shared__ float Bs[32][132];
  const int tid = threadIdx.x;
  const int tr = tid >> 4, tc = tid & 15;
  const int r0 = tr * 8, c0a = tc * 4;
  float acc[8][8] = {};
  for (int k0 = 0; k0 < NN; k0 += 32) {
    #pragma unroll
    for (int u = tid; u < 1024; u += TPB) {
      int r = u >> 3, k4 = (u & 7) << 2;
      float l = lb[r];
      float4 v = *(const float4*)(Sb + (long)(n0 + r) * NN + k0 + k4);
      As[k4 + 0][r] = expf(v.x - l);
      As[k4 + 1][r] = expf(v.y - l);
      As[k4 + 2][r] = expf(v.z - l);
      As[k4 + 3][r] = expf(v.w - l);
    }
    stage_straight(Bs, Vb + (long)k0 * DD, DD, tid);
    __syncthreads();
    mt_compute(As, Bs, r0, c0a, acc);
    __syncthreads();
  }
  #pragma unroll
  for (int i = 0; i < 8; ++i) {
    float* arow = att + ((long)btc * NN + n0 + r0 + i) * DD;
    *(float4*)(arow + c0a)      = make_float4(acc[i][0], acc[i][1], acc[i][2], acc[i][3]);
    *(float4*)(arow + c0a + 64) = make_float4(acc[i][4], acc[i][5], acc[i][6], acc[i][7]);
  }
}

// ---- gather + Wo + bias + residual + LayerNorm + FFN (fused) -> out ----
__global__ void k_wo_ln_ffn(const float* __restrict__ att, const int* __restrict__ cp,
                            const float* __restrict__ Wo, const float* __restrict__ bo,
                            const float* __restrict__ xr,
                            const float* __restrict__ W1, const float* __restrict__ b1,
                            const float* __restrict__ W2, const float* __restrict__ b2,
                            float* __restrict__ out) {
  int blk = blockIdx.x;         // btc*4 + rt
  int btc = blk >> 2, rt = blk & 3;
  int n0 = rt * 128;
  long g0 = (long)btc * NN + n0;
  const float* attb = att + (long)btc * NN * DD;
  const int* cpb = cp + g0;
  __shared__ float As[32][132];
  __shared__ float Bs[32][132];
  __shared__ float Cs[128][132];
  __shared__ float mu_s[128], rs_s[128];
  const int tid = threadIdx.x;
  const int tr = tid >> 4, tc = tid & 15;
  const int r0 = tr * 8, c0a = tc * 4;

  // --- Phase A: gathered @ Wo ---
  float acc[8][8] = {};
  for (int k0 = 0; k0 < 128; k0 += 32) {
    #pragma unroll
    for (int u = tid; u < 1024; u += TPB) {
      int r = u >> 3, k4 = (u & 7) << 2;
      int src = cpb[r];
      float4 v = *(const float4*)(attb + (long)src * DD + k0 + k4);
      As[k4 + 0][r] = v.x; As[k4 + 1][r] = v.y; As[k4 + 2][r] = v.z; As[k4 + 3][r] = v.w;
    }
    stage_straight(Bs, Wo + (long)k0 * 128, 128, tid);
    __syncthreads();
    mt_compute(As, Bs, r0, c0a, acc);
    __syncthreads();
  }
  // bias + residual into Cs
  {
    float4 blo = *(const float4*)(bo + c0a);
    float4 bhi = *(const float4*)(bo + c0a + 64);
    #pragma unroll
    for (int i = 0; i < 8; ++i) {
      const float* xrow = xr + (g0 + r0 + i) * DD;
      float4 xlo = *(const float4*)(xrow + c0a);
      float4 xhi = *(const float4*)(xrow + c0a + 64);
      Cs[r0 + i][c0a + 0]  = acc[i][0] + blo.x + xlo.x;
      Cs[r0 + i][c0a + 1]  = acc[i][1] + blo.y + xlo.y;
      Cs[r0 + i][c0a + 2]  = acc[i][2] + blo.z + xlo.z;
      Cs[r0 + i][c0a + 3]  = acc[i][3] + blo.w + xlo.w;
      Cs[r0 + i][c0a + 64] = acc[i][4] + bhi.x + xhi.x;
      Cs[r0 + i][c0a + 65] = acc[i][5] + bhi.y + xhi.y;
      Cs[r0 + i][c0a + 66] = acc[i][6] + bhi.z + xhi.z;
      Cs[r0 + i][c0a + 67] = acc[i][7] + bhi.w + xhi.w;
    }
  }
  __syncthreads();
  // LN stats: 2 threads per row
  {
    int row = tid >> 1, half = tid & 1;
    float s = 0.f, ss = 0.f;
    #pragma unroll 8
    for (int j = 0; j < 64; ++j) {
      float v = Cs[row][half * 64 + j];
      s += v; ss += v * v;
    }
    s  += __shfl_xor(s, 1);
    ss += __shfl_xor(ss, 1);
    if (half == 0) {
      float mu = s * (1.f / 128.f);
      float var = ss * (1.f / 128.f) - mu * mu;
      mu_s[row] = mu;
      rs_s[row] = rsqrtf(var + LNEPS);
    }
  }
  __syncthreads();
  // normalize in place
  for (int u = tid; u < 128 * 32; u += TPB) {
    int row = u >> 5, c4 = (u & 31) << 2;
    float mu = mu_s[row], rs = rs_s[row];
    float4 v = *(float4*)&Cs[row][c4];
    v.x = (v.x - mu) * rs; v.y = (v.y - mu) * rs;
    v.z = (v.z - mu) * rs; v.w = (v.w - mu) * rs;
    *(float4*)&Cs[row][c4] = v;
  }
  __syncthreads();

  // --- Phase B: H = relu(Cs @ W1 + b1) ---
  float acc2[8][8] = {};
  for (int k0 = 0; k0 < 128; k0 += 32) {
    stage_straight(Bs, W1 + (long)k0 * 128, 128, tid);
    __syncthreads();
    #pragma unroll
    for (int kk = 0; kk < 32; ++kk) {
      int k = k0 + kk;
      float a[8], b[8];
      #pragma unroll
      for (int i = 0; i < 8; ++i) a[i] = Cs[r0 + i][k];
      *(float4*)&b[0] = *(const float4*)&Bs[kk][c0a];
      *(float4*)&b[4] = *(const float4*)&Bs[kk][c0a + 64];
      #pragma unroll
      for (int i = 0; i < 8; ++i)
        #pragma unroll
        for (int j = 0; j < 8; ++j)
          acc2[i][j] = fmaf(a[i], b[j], acc2[i][j]);
    }
    __syncthreads();
  }
  // bias + relu, write H^T into Cs (Cs[col][row])
  {
    float4 b1lo = *(const float4*)(b1 + c0a);
    float4 b1hi = *(const float4*)(b1 + c0a + 64);
    #pragma unroll
    for (int i = 0; i < 8; ++i) {
      Cs[c0a + 0][r0 + i]  = fmaxf(acc2[i][0] + b1lo.x, 0.f);
      Cs[c0a + 1][r0 + i]  = fmaxf(acc2[i][1] + b1lo.y, 0.f);
      Cs[c0a + 2][r0 + i]  = fmaxf(acc2[i][2] + b1lo.z, 0.f);
      Cs[c0a + 3][r0 + i]  = fmaxf(acc2[i][3] + b1lo.w, 0.f);
      Cs[c0a + 64][r0 + i] = fmaxf(acc2[i][4] + b1hi.x, 0.f);
      Cs[c0a + 65][r0 + i] = fmaxf(acc2[i][5] + b1hi.y, 0.f);
      Cs[c0a + 66][r0 + i] = fmaxf(acc2[i][6] + b1hi.z, 0.f);
      Cs[c0a + 67][r0 + i] = fmaxf(acc2[i][7] + b1hi.w, 0.f);
    }
  }
  __syncthreads();

  // --- Phase C: out = H @ W2 + b2 (Cs now holds H^T = As layout) ---
  float acc3[8][8] = {};
  for (int k0 = 0; k0 < 128; k0 += 32) {
    stage_straight(Bs, W2 + (long)k0 * 128, 128, tid);
    __syncthreads();
    mt_compute((const float(*)[132])&Cs[k0][0], Bs, r0, c0a, acc3);
    __syncthreads();
  }
  {
    float4 b2lo = *(const float4*)(b2 + c0a);
    float4 b2hi = *(const float4*)(b2 + c0a + 64);
    #pragma unroll
    for (int i = 0; i < 8; ++i) {
      float* orow = out + (g0 + r0 + i) * DD;
      *(float4*)(orow + c0a) = make_float4(acc3[i][0] + b2lo.x, acc3[i][1] + b2lo.y,
                                           acc3[i][2] + b2lo.z, acc3[i][3] + b2lo.w);
      *(float4*)(orow + c0a + 64) = make_float4(acc3[i][4] + b2hi.x, acc3[i][5] + b2hi.y,
                                                acc3[i][6] + b2hi.z, acc3[i][7] + b2hi.w);
    }
  }
}

// ---------------- launch ----------------
extern "C" void kernel_launch(void* const* d_in, const int* in_sizes, int n_in,
                              void* d_out, int out_size, void* d_ws, size_t ws_size,
                              hipStream_t stream) {
  const float* x    = (const float*)d_in[0];
  const float* adj  = (const float*)d_in[1];
  const float* Wq   = (const float*)d_in[2];
  const float* bq   = (const float*)d_in[3];
  const float* Wk   = (const float*)d_in[4];
  const float* bk   = (const float*)d_in[5];
  const float* Wv   = (const float*)d_in[6];
  const float* bv   = (const float*)d_in[7];
  const float* Wo   = (const float*)d_in[8];
  const float* bo   = (const float*)d_in[9];
  const float* W1   = (const float*)d_in[10];
  const float* b1   = (const float*)d_in[11];
  const float* W2   = (const float*)d_in[12];
  const float* b2   = (const float*)d_in[13];
  float* out = (float*)d_out;
  (void)in_sizes; (void)n_in; (void)out_size;

  // per-bt workspace cost: xr/Q/K/V/att (0.25 MiB each) + S (1 MiB) + lse/cp
  const size_t BT_ROWBYTES = (size_t)NN * DD * 4;                 // 262144
  const size_t per_bt = 5 * BT_ROWBYTES + (size_t)NN * NN * 4 + 2 * (size_t)NN * 4;
  static const int divs[] = {192, 96, 64, 48, 32, 24, 16, 12, 8, 6, 4, 3, 2, 1};
  int CH = 1;
  for (int i = 0; i < 14; ++i) {
    if ((size_t)divs[i] * per_bt + 8192 <= ws_size) { CH = divs[i]; break; }
  }

  char* ws = (char*)d_ws;
  size_t off = 0;
  auto alloc = [&](size_t bytes) -> void* {
    void* p = ws + off;
    off += (bytes + 255) & ~(size_t)255;
    return p;
  };
  float* xrc  = (float*)alloc((size_t)CH * BT_ROWBYTES);
  float* Qc   = (float*)alloc((size_t)CH * BT_ROWBYTES);
  float* Kc   = (float*)alloc((size_t)CH * BT_ROWBYTES);
  float* Vc   = (float*)alloc((size_t)CH * BT_ROWBYTES);
  float* attc = (float*)alloc((size_t)CH * BT_ROWBYTES);
  float* Sc   = (float*)alloc((size_t)CH * NN * NN * 4);
  float* lsec = (float*)alloc((size_t)CH * NN * 4);
  int*   cpc  = (int*)  alloc((size_t)CH * NN * 4);

  for (int c0 = 0; c0 < BTT; c0 += CH) {
    const size_t elemoff = (size_t)c0 * NN * DD;
    const float* xb  = x + elemoff;
    const float* ab  = adj + elemoff;
    float* outb = out + elemoff;
    int n4c = CH * NN * DD / 4;

    k_add<<<n4c / TPB, TPB, 0, stream>>>(xb, ab, xrc, n4c);

    k_gemm_bias<<<CH * 4, TPB, 0, stream>>>(xrc, Wq, bq, Qc);
    k_gemm_bias<<<CH * 4, TPB, 0, stream>>>(xrc, Wk, bk, Kc);
    k_gemm_bias<<<CH * 4, TPB, 0, stream>>>(xrc, Wv, bv, Vc);

    k_scores<<<CH * 16, TPB, 0, stream>>>(Qc, Kc, Sc);
    k_lse<<<CH * 128, TPB, 0, stream>>>(Sc, lsec);
    k_colargmax<<<CH * 2, TPB, 0, stream>>>(Sc, lsec, cpc);
    k_pv<<<CH * 4, TPB, 0, stream>>>(Sc, lsec, Vc, attc);

    k_wo_ln_ffn<<<CH * 4, TPB, 0, stream>>>(attc, cpc, Wo, bo, xrc,
                                            W1, b1, W2, b2, outb);
  }
}

// Round 4
// 1000.093 us; speedup vs baseline: 2.2051x; 2.2051x over previous
//
#include <hip/hip_runtime.h>
#include <math.h>

#define TPB 256
static constexpr int BTT = 192;    // B*T
static constexpr int NN  = 512;    // nodes
static constexpr int DD  = 128;    // feature dim
static constexpr float SCALE = 0.25f; // 1/sqrt(16)
static constexpr float LNEPS = 1e-5f;

typedef _Float16 half8 __attribute__((ext_vector_type(8)));
typedef float floatx4 __attribute__((ext_vector_type(4)));

// ---------------- elementwise add (chunk) ----------------
__global__ void k_add(const float* __restrict__ x, const float* __restrict__ g,
                      float* __restrict__ y, int n4) {
  int i = blockIdx.x * blockDim.x + threadIdx.x;
  if (i < n4) {
    const float4* xa = (const float4*)x;
    const float4* ga = (const float4*)g;
    float4 a = xa[i], b = ga[i];
    ((float4*)y)[i] = make_float4(a.x + b.x, a.y + b.y, a.z + b.z, a.w + b.w);
  }
}

// ---------------- shared GEMM micro-kernel pieces (fp32) ----------------
__device__ __forceinline__ void stage_straight(float (*Bs)[132], const float* __restrict__ src,
                                               int ld, int tid) {
  #pragma unroll
  for (int u = tid; u < 1024; u += TPB) {
    int kk = u >> 5, c4 = (u & 31) << 2;
    *(float4*)&Bs[kk][c4] = *(const float4*)(src + (long)kk * ld + c4);
  }
}

__device__ __forceinline__ void stage_transposed(float (*As)[132], const float* __restrict__ src,
                                                 int ld, int tid) {
  #pragma unroll
  for (int u = tid; u < 1024; u += TPB) {
    int r = u >> 3, k4 = (u & 7) << 2;
    float4 v = *(const float4*)(src + (long)r * ld + k4);
    As[k4 + 0][r] = v.x; As[k4 + 1][r] = v.y; As[k4 + 2][r] = v.z; As[k4 + 3][r] = v.w;
  }
}

__device__ __forceinline__ void mt_compute(const float (*As)[132], const float (*Bs)[132],
                                           int r0, int c0a, float acc[8][8]) {
  #pragma unroll
  for (int kk = 0; kk < 32; ++kk) {
    float a[8], b[8];
    *(float4*)&a[0] = *(const float4*)&As[kk][r0];
    *(float4*)&a[4] = *(const float4*)&As[kk][r0 + 4];
    *(float4*)&b[0] = *(const float4*)&Bs[kk][c0a];
    *(float4*)&b[4] = *(const float4*)&Bs[kk][c0a + 64];
    #pragma unroll
    for (int i = 0; i < 8; ++i)
      #pragma unroll
      for (int j = 0; j < 8; ++j)
        acc[i][j] = fmaf(a[i], b[j], acc[i][j]);
  }
}

// ---------------- GEMM + bias: C[M,128] = A[M,128]@W[128,128]+b ----------------
__global__ __launch_bounds__(TPB, 2)
void k_gemm_bias(const float* __restrict__ A, const float* __restrict__ W,
                 const float* __restrict__ bias, float* __restrict__ C) {
  __shared__ float As[32][132];
  __shared__ float Bs[32][132];
  const int tid = threadIdx.x;
  const int tr = tid >> 4, tc = tid & 15;
  const int r0 = tr * 8, c0a = tc * 4;
  const long rowblk = (long)blockIdx.x * 128;
  float acc[8][8] = {};
  for (int k0 = 0; k0 < 128; k0 += 32) {
    stage_transposed(As, A + rowblk * 128 + k0, 128, tid);
    stage_straight(Bs, W + (long)k0 * 128, 128, tid);
    __syncthreads();
    mt_compute(As, Bs, r0, c0a, acc);
    __syncthreads();
  }
  float4 blo = *(const float4*)(bias + c0a);
  float4 bhi = *(const float4*)(bias + c0a + 64);
  #pragma unroll
  for (int i = 0; i < 8; ++i) {
    float* crow = C + (rowblk + r0 + i) * 128;
    *(float4*)(crow + c0a) = make_float4(acc[i][0] + blo.x, acc[i][1] + blo.y,
                                         acc[i][2] + blo.z, acc[i][3] + blo.w);
    *(float4*)(crow + c0a + 64) = make_float4(acc[i][4] + bhi.x, acc[i][5] + bhi.y,
                                              acc[i][6] + bhi.z, acc[i][7] + bhi.w);
  }
}

// ---------------- scores: S[btc][n][m] = Q[btc][n]·K[btc][m] * 0.25 ----------------
__global__ __launch_bounds__(TPB, 2)
void k_scores(const float* __restrict__ Q, const float* __restrict__ K,
              float* __restrict__ S) {
  int blk = blockIdx.x;            // btc*16 + rt*4 + ct
  int btc = blk >> 4, rt = (blk >> 2) & 3, ct = blk & 3;
  const float* Qb = Q + (long)btc * NN * DD;
  const float* Kb = K + (long)btc * NN * DD;
  float* Sb = S + (long)btc * NN * NN;
  int n0 = rt * 128, m0 = ct * 128;
  __shared__ float As[32][132];
  __shared__ float Bs[32][132];
  const int tid = threadIdx.x;
  const int tr = tid >> 4, tc = tid & 15;
  const int r0 = tr * 8, c0a = tc * 4;
  float acc[8][8] = {};
  for (int k0 = 0; k0 < 128; k0 += 32) {
    stage_transposed(As, Qb + (long)n0 * 128 + k0, 128, tid);
    stage_transposed(Bs, Kb + (long)m0 * 128 + k0, 128, tid);  // K^T
    __syncthreads();
    mt_compute(As, Bs, r0, c0a, acc);
    __syncthreads();
  }
  #pragma unroll
  for (int i = 0; i < 8; ++i) {
    float* srow = Sb + (long)(n0 + r0 + i) * NN + m0;
    *(float4*)(srow + c0a) = make_float4(acc[i][0] * SCALE, acc[i][1] * SCALE,
                                         acc[i][2] * SCALE, acc[i][3] * SCALE);
    *(float4*)(srow + c0a + 64) = make_float4(acc[i][4] * SCALE, acc[i][5] * SCALE,
                                              acc[i][6] * SCALE, acc[i][7] * SCALE);
  }
}

// ---------------- row LSE over 512 (unchanged — argmax-critical) ----------------
__global__ void k_lse(const float* __restrict__ S, float* __restrict__ lse) {
  int w = threadIdx.x >> 6, lane = threadIdx.x & 63;
  long row = (long)blockIdx.x * 4 + w;
  const float4* p = (const float4*)(S + row * NN);
  float4 a = p[lane], b = p[lane + 64];
  float m = fmaxf(fmaxf(fmaxf(a.x, a.y), fmaxf(a.z, a.w)),
                  fmaxf(fmaxf(b.x, b.y), fmaxf(b.z, b.w)));
  #pragma unroll
  for (int d = 1; d < 64; d <<= 1) m = fmaxf(m, __shfl_xor(m, d));
  float s = expf(a.x - m) + expf(a.y - m) + expf(a.z - m) + expf(a.w - m)
          + expf(b.x - m) + expf(b.y - m) + expf(b.z - m) + expf(b.w - m);
  #pragma unroll
  for (int d = 1; d < 64; d <<= 1) s += __shfl_xor(s, d);
  if (lane == 0) lse[row] = m + logf(s);
}

// ---------------- column argmax (unchanged — argmax-critical) ----------------
__global__ void k_colargmax(const float* __restrict__ S, const float* __restrict__ lse,
                            int* __restrict__ cp) {
  int btc = blockIdx.x >> 1;
  int col = ((blockIdx.x & 1) << 8) + threadIdx.x;
  const float* Sb = S + (long)btc * NN * NN;
  const float* lb = lse + btc * NN;
  float best = -1e30f;
  int bi = 0;
  for (int n = 0; n < NN; ++n) {
    float v = Sb[(long)n * NN + col] - lb[n];
    if (v > best) { best = v; bi = n; }    // strict > keeps first index (jnp.argmax)
  }
  cp[btc * NN + col] = bi;
}

// ---------------- PV via fp16 MFMA: attended = exp(S - lse) @ V ----------------
// A = P [n][m] (row-major, k=m contiguous); B = V^T staged [d][m] (k=m contiguous).
// mfma_f32_16x16x32_f16: A lane l holds A[l&15][(l>>4)*8 + j]; B lane l holds
// B[(l>>4)*8 + j][l&15]; D lane l reg r = D[(l>>4)*4 + r][l&15] (m89-verified C/D).
__global__ __launch_bounds__(TPB, 2)
void k_pv_f16(const float* __restrict__ S, const float* __restrict__ lse,
              const float* __restrict__ V, float* __restrict__ att) {
  int btc = blockIdx.x >> 2, nt = blockIdx.x & 3;
  const int n0 = nt * 128;
  const float* Sb = S + (long)btc * NN * NN + (long)n0 * NN;
  const float* lb = lse + btc * NN + n0;
  const float* Vb = V + (long)btc * NN * DD;
  float* attb = att + ((long)btc * NN + n0) * DD;

  __shared__ _Float16 Ph[128][72];   // P chunk [n][64 m + pad]
  __shared__ _Float16 Vt[128][72];   // V^T chunk [d][64 m + pad]

  const int tid = threadIdx.x;
  const int lane = tid & 63;
  const int wave = tid >> 6;          // wave owns n-rows [wave*32, wave*32+32)
  const int frow = lane & 15;         // fragment row (A) / col (B,D)
  const int kgrp = lane >> 4;         // k-group: elements k = kgrp*8 + j

  floatx4 acc[2][8];
  #pragma unroll
  for (int i = 0; i < 2; ++i)
    #pragma unroll
    for (int j = 0; j < 8; ++j)
      acc[i][j] = (floatx4){0.f, 0.f, 0.f, 0.f};

  for (int m0 = 0; m0 < NN; m0 += 64) {
    __syncthreads();
    // stage P = exp(S - lse) -> f16, 128 n x 64 m
    for (int u = tid; u < 128 * 16; u += TPB) {
      int n = u >> 4, m4 = (u & 15) << 2;
      float l = lb[n];
      float4 s4 = *(const float4*)(Sb + (long)n * NN + m0 + m4);
      Ph[n][m4 + 0] = (_Float16)__expf(s4.x - l);
      Ph[n][m4 + 1] = (_Float16)__expf(s4.y - l);
      Ph[n][m4 + 2] = (_Float16)__expf(s4.z - l);
      Ph[n][m4 + 3] = (_Float16)__expf(s4.w - l);
    }
    // stage V^T -> f16: Vt[d][m] from V[m0+m][d]; lanes cover a full 512B row
    for (int u = tid; u < 64 * 32; u += TPB) {
      int d4 = (u & 31) << 2, m = u >> 5;
      float4 v4 = *(const float4*)(Vb + (long)(m0 + m) * DD + d4);
      Vt[d4 + 0][m] = (_Float16)v4.x;
      Vt[d4 + 1][m] = (_Float16)v4.y;
      Vt[d4 + 2][m] = (_Float16)v4.z;
      Vt[d4 + 3][m] = (_Float16)v4.w;
    }
    __syncthreads();
    // 2 k-steps of 32 within the 64-m chunk
    #pragma unroll
    for (int ks = 0; ks < 2; ++ks) {
      const int mk = ks * 32 + kgrp * 8;
      half8 a0 = *(const half8*)&Ph[wave * 32 + frow][mk];
      half8 a1 = *(const half8*)&Ph[wave * 32 + 16 + frow][mk];
      #pragma unroll
      for (int j = 0; j < 8; ++j) {
        half8 b = *(const half8*)&Vt[j * 16 + frow][mk];
        acc[0][j] = __builtin_amdgcn_mfma_f32_16x16x32_f16(a0, b, acc[0][j], 0, 0, 0);
        acc[1][j] = __builtin_amdgcn_mfma_f32_16x16x32_f16(a1, b, acc[1][j], 0, 0, 0);
      }
    }
  }
  // write attended[n][d]: n = wave*32 + i*16 + kgrp*4 + r, d = j*16 + frow
  #pragma unroll
  for (int i = 0; i < 2; ++i)
    #pragma unroll
    for (int j = 0; j < 8; ++j)
      #pragma unroll
      for (int r = 0; r < 4; ++r)
        attb[(long)(wave * 32 + i * 16 + kgrp * 4 + r) * DD + j * 16 + frow] = acc[i][j][r];
}

// ---- gather + Wo + bias + residual + LayerNorm + FFN (fused) -> out ----
__global__ __launch_bounds__(TPB, 1)
void k_wo_ln_ffn(const float* __restrict__ att, const int* __restrict__ cp,
                 const float* __restrict__ Wo, const float* __restrict__ bo,
                 const float* __restrict__ xr,
                 const float* __restrict__ W1, const float* __restrict__ b1,
                 const float* __restrict__ W2, const float* __restrict__ b2,
                 float* __restrict__ out) {
  int blk = blockIdx.x;         // btc*4 + rt
  int btc = blk >> 2, rt = blk & 3;
  int n0 = rt * 128;
  long g0 = (long)btc * NN + n0;
  const float* attb = att + (long)btc * NN * DD;
  const int* cpb = cp + g0;
  __shared__ float As[32][132];
  __shared__ float Bs[32][132];
  __shared__ float Cs[128][132];
  __shared__ float mu_s[128], rs_s[128];
  const int tid = threadIdx.x;
  const int tr = tid >> 4, tc = tid & 15;
  const int r0 = tr * 8, c0a = tc * 4;

  // --- Phase A: gathered @ Wo ---
  float acc[8][8] = {};
  for (int k0 = 0; k0 < 128; k0 += 32) {
    #pragma unroll
    for (int u = tid; u < 1024; u += TPB) {
      int r = u >> 3, k4 = (u & 7) << 2;
      int src = cpb[r];
      float4 v = *(const float4*)(attb + (long)src * DD + k0 + k4);
      As[k4 + 0][r] = v.x; As[k4 + 1][r] = v.y; As[k4 + 2][r] = v.z; As[k4 + 3][r] = v.w;
    }
    stage_straight(Bs, Wo + (long)k0 * 128, 128, tid);
    __syncthreads();
    mt_compute(As, Bs, r0, c0a, acc);
    __syncthreads();
  }
  // bias + residual into Cs
  {
    float4 blo = *(const float4*)(bo + c0a);
    float4 bhi = *(const float4*)(bo + c0a + 64);
    #pragma unroll
    for (int i = 0; i < 8; ++i) {
      const float* xrow = xr + (g0 + r0 + i) * DD;
      float4 xlo = *(const float4*)(xrow + c0a);
      float4 xhi = *(const float4*)(xrow + c0a + 64);
      Cs[r0 + i][c0a + 0]  = acc[i][0] + blo.x + xlo.x;
      Cs[r0 + i][c0a + 1]  = acc[i][1] + blo.y + xlo.y;
      Cs[r0 + i][c0a + 2]  = acc[i][2] + blo.z + xlo.z;
      Cs[r0 + i][c0a + 3]  = acc[i][3] + blo.w + xlo.w;
      Cs[r0 + i][c0a + 64] = acc[i][4] + bhi.x + xhi.x;
      Cs[r0 + i][c0a + 65] = acc[i][5] + bhi.y + xhi.y;
      Cs[r0 + i][c0a + 66] = acc[i][6] + bhi.z + xhi.z;
      Cs[r0 + i][c0a + 67] = acc[i][7] + bhi.w + xhi.w;
    }
  }
  __syncthreads();
  // LN stats: 2 threads per row
  {
    int row = tid >> 1, half = tid & 1;
    float s = 0.f, ss = 0.f;
    #pragma unroll 8
    for (int j = 0; j < 64; ++j) {
      float v = Cs[row][half * 64 + j];
      s += v; ss += v * v;
    }
    s  += __shfl_xor(s, 1);
    ss += __shfl_xor(ss, 1);
    if (half == 0) {
      float mu = s * (1.f / 128.f);
      float var = ss * (1.f / 128.f) - mu * mu;
      mu_s[row] = mu;
      rs_s[row] = rsqrtf(var + LNEPS);
    }
  }
  __syncthreads();
  // normalize in place
  for (int u = tid; u < 128 * 32; u += TPB) {
    int row = u >> 5, c4 = (u & 31) << 2;
    float mu = mu_s[row], rs = rs_s[row];
    float4 v = *(float4*)&Cs[row][c4];
    v.x = (v.x - mu) * rs; v.y = (v.y - mu) * rs;
    v.z = (v.z - mu) * rs; v.w = (v.w - mu) * rs;
    *(float4*)&Cs[row][c4] = v;
  }
  __syncthreads();

  // --- Phase B: H = relu(Cs @ W1 + b1) ---
  float acc2[8][8] = {};
  for (int k0 = 0; k0 < 128; k0 += 32) {
    stage_straight(Bs, W1 + (long)k0 * 128, 128, tid);
    __syncthreads();
    #pragma unroll
    for (int kk = 0; kk < 32; ++kk) {
      int k = k0 + kk;
      float a[8], b[8];
      #pragma unroll
      for (int i = 0; i < 8; ++i) a[i] = Cs[r0 + i][k];
      *(float4*)&b[0] = *(const float4*)&Bs[kk][c0a];
      *(float4*)&b[4] = *(const float4*)&Bs[kk][c0a + 64];
      #pragma unroll
      for (int i = 0; i < 8; ++i)
        #pragma unroll
        for (int j = 0; j < 8; ++j)
          acc2[i][j] = fmaf(a[i], b[j], acc2[i][j]);
    }
    __syncthreads();
  }
  // bias + relu, write H^T into Cs (Cs[col][row])
  {
    float4 b1lo = *(const float4*)(b1 + c0a);
    float4 b1hi = *(const float4*)(b1 + c0a + 64);
    #pragma unroll
    for (int i = 0; i < 8; ++i) {
      Cs[c0a + 0][r0 + i]  = fmaxf(acc2[i][0] + b1lo.x, 0.f);
      Cs[c0a + 1][r0 + i]  = fmaxf(acc2[i][1] + b1lo.y, 0.f);
      Cs[c0a + 2][r0 + i]  = fmaxf(acc2[i][2] + b1lo.z, 0.f);
      Cs[c0a + 3][r0 + i]  = fmaxf(acc2[i][3] + b1lo.w, 0.f);
      Cs[c0a + 64][r0 + i] = fmaxf(acc2[i][4] + b1hi.x, 0.f);
      Cs[c0a + 65][r0 + i] = fmaxf(acc2[i][5] + b1hi.y, 0.f);
      Cs[c0a + 66][r0 + i] = fmaxf(acc2[i][6] + b1hi.z, 0.f);
      Cs[c0a + 67][r0 + i] = fmaxf(acc2[i][7] + b1hi.w, 0.f);
    }
  }
  __syncthreads();

  // --- Phase C: out = H @ W2 + b2 (Cs holds H^T in As layout) ---
  float acc3[8][8] = {};
  for (int k0 = 0; k0 < 128; k0 += 32) {
    stage_straight(Bs, W2 + (long)k0 * 128, 128, tid);
    __syncthreads();
    mt_compute((const float(*)[132])&Cs[k0][0], Bs, r0, c0a, acc3);
    __syncthreads();
  }
  {
    float4 b2lo = *(const float4*)(b2 + c0a);
    float4 b2hi = *(const float4*)(b2 + c0a + 64);
    #pragma unroll
    for (int i = 0; i < 8; ++i) {
      float* orow = out + (g0 + r0 + i) * DD;
      *(float4*)(orow + c0a) = make_float4(acc3[i][0] + b2lo.x, acc3[i][1] + b2lo.y,
                                           acc3[i][2] + b2lo.z, acc3[i][3] + b2lo.w);
      *(float4*)(orow + c0a + 64) = make_float4(acc3[i][4] + b2hi.x, acc3[i][5] + b2hi.y,
                                                acc3[i][6] + b2hi.z, acc3[i][7] + b2hi.w);
    }
  }
}

// ---------------- launch ----------------
extern "C" void kernel_launch(void* const* d_in, const int* in_sizes, int n_in,
                              void* d_out, int out_size, void* d_ws, size_t ws_size,
                              hipStream_t stream) {
  const float* x    = (const float*)d_in[0];
  const float* adj  = (const float*)d_in[1];
  const float* Wq   = (const float*)d_in[2];
  const float* bq   = (const float*)d_in[3];
  const float* Wk   = (const float*)d_in[4];
  const float* bk   = (const float*)d_in[5];
  const float* Wv   = (const float*)d_in[6];
  const float* bv   = (const float*)d_in[7];
  const float* Wo   = (const float*)d_in[8];
  const float* bo   = (const float*)d_in[9];
  const float* W1   = (const float*)d_in[10];
  const float* b1   = (const float*)d_in[11];
  const float* W2   = (const float*)d_in[12];
  const float* b2   = (const float*)d_in[13];
  float* out = (float*)d_out;
  (void)in_sizes; (void)n_in; (void)out_size;

  // per-bt workspace: xr/Q/K/V/att (0.25 MiB each) + S (1 MiB) + lse/cp
  const size_t BT_ROWBYTES = (size_t)NN * DD * 4;                 // 262144
  const size_t per_bt = 5 * BT_ROWBYTES + (size_t)NN * NN * 4 + 2 * (size_t)NN * 4;
  static const int divs[] = {192, 96, 64, 48, 32, 24, 16, 12, 8, 6, 4, 3, 2, 1};
  int CH = 1;
  for (int i = 0; i < 14; ++i) {
    if ((size_t)divs[i] * per_bt + 8192 <= ws_size) { CH = divs[i]; break; }
  }

  char* ws = (char*)d_ws;
  size_t off = 0;
  auto alloc = [&](size_t bytes) -> void* {
    void* p = ws + off;
    off += (bytes + 255) & ~(size_t)255;
    return p;
  };
  float* xrc  = (float*)alloc((size_t)CH * BT_ROWBYTES);
  float* Qc   = (float*)alloc((size_t)CH * BT_ROWBYTES);
  float* Kc   = (float*)alloc((size_t)CH * BT_ROWBYTES);
  float* Vc   = (float*)alloc((size_t)CH * BT_ROWBYTES);
  float* attc = (float*)alloc((size_t)CH * BT_ROWBYTES);
  float* Sc   = (float*)alloc((size_t)CH * NN * NN * 4);
  float* lsec = (float*)alloc((size_t)CH * NN * 4);
  int*   cpc  = (int*)  alloc((size_t)CH * NN * 4);

  for (int c0 = 0; c0 < BTT; c0 += CH) {
    const size_t elemoff = (size_t)c0 * NN * DD;
    const float* xb  = x + elemoff;
    const float* ab  = adj + elemoff;
    float* outb = out + elemoff;
    int n4c = CH * NN * DD / 4;

    k_add<<<n4c / TPB, TPB, 0, stream>>>(xb, ab, xrc, n4c);

    k_gemm_bias<<<CH * 4, TPB, 0, stream>>>(xrc, Wq, bq, Qc);
    k_gemm_bias<<<CH * 4, TPB, 0, stream>>>(xrc, Wk, bk, Kc);
    k_gemm_bias<<<CH * 4, TPB, 0, stream>>>(xrc, Wv, bv, Vc);

    k_scores<<<CH * 16, TPB, 0, stream>>>(Qc, Kc, Sc);
    k_lse<<<CH * 128, TPB, 0, stream>>>(Sc, lsec);
    k_colargmax<<<CH * 2, TPB, 0, stream>>>(Sc, lsec, cpc);
    k_pv_f16<<<CH * 4, TPB, 0, stream>>>(Sc, lsec, Vc, attc);

    k_wo_ln_ffn<<<CH * 4, TPB, 0, stream>>>(attc, cpc, Wo, bo, xrc,
                                            W1, b1, W2, b2, outb);
  }
}

// Round 5
// 838.640 us; speedup vs baseline: 2.6296x; 1.1925x over previous
//
#include <hip/hip_runtime.h>
#include <math.h>

#define TPB 256
static constexpr int BTT = 192;    // B*T
static constexpr int NN  = 512;    // nodes
static constexpr int DD  = 128;    // feature dim
static constexpr float SCALE = 0.25f; // 1/sqrt(16)
static constexpr float LNEPS = 1e-5f;

typedef _Float16 half8 __attribute__((ext_vector_type(8)));
typedef float floatx4 __attribute__((ext_vector_type(4)));

// ---------------- elementwise add (chunk) ----------------
__global__ void k_add(const float* __restrict__ x, const float* __restrict__ g,
                      float* __restrict__ y, int n4) {
  int i = blockIdx.x * blockDim.x + threadIdx.x;
  if (i < n4) {
    const float4* xa = (const float4*)x;
    const float4* ga = (const float4*)g;
    float4 a = xa[i], b = ga[i];
    ((float4*)y)[i] = make_float4(a.x + b.x, a.y + b.y, a.z + b.z, a.w + b.w);
  }
}

// ---------------- shared fp32 GEMM micro-kernel pieces ----------------
__device__ __forceinline__ void stage_straight(float (*Bs)[132], const float* __restrict__ src,
                                               int ld, int tid) {
  #pragma unroll
  for (int u = tid; u < 1024; u += TPB) {
    int kk = u >> 5, c4 = (u & 31) << 2;
    *(float4*)&Bs[kk][c4] = *(const float4*)(src + (long)kk * ld + c4);
  }
}

__device__ __forceinline__ void stage_transposed(float (*As)[132], const float* __restrict__ src,
                                                 int ld, int tid) {
  #pragma unroll
  for (int u = tid; u < 1024; u += TPB) {
    int r = u >> 3, k4 = (u & 7) << 2;
    float4 v = *(const float4*)(src + (long)r * ld + k4);
    As[k4 + 0][r] = v.x; As[k4 + 1][r] = v.y; As[k4 + 2][r] = v.z; As[k4 + 3][r] = v.w;
  }
}

__device__ __forceinline__ void mt_compute(const float (*As)[132], const float (*Bs)[132],
                                           int r0, int c0a, float acc[8][8]) {
  #pragma unroll
  for (int kk = 0; kk < 32; ++kk) {
    float a[8], b[8];
    *(float4*)&a[0] = *(const float4*)&As[kk][r0];
    *(float4*)&a[4] = *(const float4*)&As[kk][r0 + 4];
    *(float4*)&b[0] = *(const float4*)&Bs[kk][c0a];
    *(float4*)&b[4] = *(const float4*)&Bs[kk][c0a + 64];
    #pragma unroll
    for (int i = 0; i < 8; ++i)
      #pragma unroll
      for (int j = 0; j < 8; ++j)
        acc[i][j] = fmaf(a[i], b[j], acc[i][j]);
  }
}

// ---------------- GEMM + bias (fp32, argmax-critical inputs) ----------------
__global__ __launch_bounds__(TPB, 2)
void k_gemm_bias(const float* __restrict__ A, const float* __restrict__ W,
                 const float* __restrict__ bias, float* __restrict__ C) {
  __shared__ float As[32][132];
  __shared__ float Bs[32][132];
  const int tid = threadIdx.x;
  const int tr = tid >> 4, tc = tid & 15;
  const int r0 = tr * 8, c0a = tc * 4;
  const long rowblk = (long)blockIdx.x * 128;
  float acc[8][8] = {};
  for (int k0 = 0; k0 < 128; k0 += 32) {
    stage_transposed(As, A + rowblk * 128 + k0, 128, tid);
    stage_straight(Bs, W + (long)k0 * 128, 128, tid);
    __syncthreads();
    mt_compute(As, Bs, r0, c0a, acc);
    __syncthreads();
  }
  float4 blo = *(const float4*)(bias + c0a);
  float4 bhi = *(const float4*)(bias + c0a + 64);
  #pragma unroll
  for (int i = 0; i < 8; ++i) {
    float* crow = C + (rowblk + r0 + i) * 128;
    *(float4*)(crow + c0a) = make_float4(acc[i][0] + blo.x, acc[i][1] + blo.y,
                                         acc[i][2] + blo.z, acc[i][3] + blo.w);
    *(float4*)(crow + c0a + 64) = make_float4(acc[i][4] + bhi.x, acc[i][5] + bhi.y,
                                              acc[i][6] + bhi.z, acc[i][7] + bhi.w);
  }
}

// ---------------- scores: S = Q·K^T * 0.25 (fp32, argmax-critical) ----------------
__global__ __launch_bounds__(TPB, 2)
void k_scores(const float* __restrict__ Q, const float* __restrict__ K,
              float* __restrict__ S) {
  int blk = blockIdx.x;            // btc*16 + rt*4 + ct
  int btc = blk >> 4, rt = (blk >> 2) & 3, ct = blk & 3;
  const float* Qb = Q + (long)btc * NN * DD;
  const float* Kb = K + (long)btc * NN * DD;
  float* Sb = S + (long)btc * NN * NN;
  int n0 = rt * 128, m0 = ct * 128;
  __shared__ float As[32][132];
  __shared__ float Bs[32][132];
  const int tid = threadIdx.x;
  const int tr = tid >> 4, tc = tid & 15;
  const int r0 = tr * 8, c0a = tc * 4;
  float acc[8][8] = {};
  for (int k0 = 0; k0 < 128; k0 += 32) {
    stage_transposed(As, Qb + (long)n0 * 128 + k0, 128, tid);
    stage_transposed(Bs, Kb + (long)m0 * 128 + k0, 128, tid);  // K^T
    __syncthreads();
    mt_compute(As, Bs, r0, c0a, acc);
    __syncthreads();
  }
  #pragma unroll
  for (int i = 0; i < 8; ++i) {
    float* srow = Sb + (long)(n0 + r0 + i) * NN + m0;
    *(float4*)(srow + c0a) = make_float4(acc[i][0] * SCALE, acc[i][1] * SCALE,
                                         acc[i][2] * SCALE, acc[i][3] * SCALE);
    *(float4*)(srow + c0a + 64) = make_float4(acc[i][4] * SCALE, acc[i][5] * SCALE,
                                              acc[i][6] * SCALE, acc[i][7] * SCALE);
  }
}

// ---------------- row LSE over 512 (unchanged — argmax-critical) ----------------
__global__ void k_lse(const float* __restrict__ S, float* __restrict__ lse) {
  int w = threadIdx.x >> 6, lane = threadIdx.x & 63;
  long row = (long)blockIdx.x * 4 + w;
  const float4* p = (const float4*)(S + row * NN);
  float4 a = p[lane], b = p[lane + 64];
  float m = fmaxf(fmaxf(fmaxf(a.x, a.y), fmaxf(a.z, a.w)),
                  fmaxf(fmaxf(b.x, b.y), fmaxf(b.z, b.w)));
  #pragma unroll
  for (int d = 1; d < 64; d <<= 1) m = fmaxf(m, __shfl_xor(m, d));
  float s = expf(a.x - m) + expf(a.y - m) + expf(a.z - m) + expf(a.w - m)
          + expf(b.x - m) + expf(b.y - m) + expf(b.z - m) + expf(b.w - m);
  #pragma unroll
  for (int d = 1; d < 64; d <<= 1) s += __shfl_xor(s, d);
  if (lane == 0) lse[row] = m + logf(s);
}

// ---------------- column argmax, 4-way split over rows ----------------
// cp[btc][m] = first argmax_n (S[n][m] - lse[n]); segments merged in ascending
// order with strict > so tie-breaking matches a full sequential first-max scan.
__global__ __launch_bounds__(TPB)
void k_colargmax(const float* __restrict__ S, const float* __restrict__ lse,
                 int* __restrict__ cp) {
  int btc = blockIdx.x >> 3, cg = blockIdx.x & 7;
  int c = threadIdx.x & 63;
  int col = cg * 64 + c;
  int seg = threadIdx.x >> 6;          // 0..3 -> rows [seg*128, seg*128+128)
  const float* Sb = S + (long)btc * NN * NN;
  const float* lb = lse + btc * NN;
  float best = -3.4e38f;
  int bi = seg * 128;
  for (int n = seg * 128; n < seg * 128 + 128; ++n) {
    float v = Sb[(long)n * NN + col] - lb[n];
    if (v > best) { best = v; bi = n; }
  }
  __shared__ float bv[4][64];
  __shared__ int bidx[4][64];
  bv[seg][c] = best; bidx[seg][c] = bi;
  __syncthreads();
  if (seg == 0) {
    #pragma unroll
    for (int s = 1; s < 4; ++s) {
      float v2 = bv[s][c];
      if (v2 > best) { best = v2; bi = bidx[s][c]; }
    }
    cp[btc * NN + col] = bi;
  }
}

// ---------------- PV via fp16 MFMA (verified layout) ----------------
__global__ __launch_bounds__(TPB, 2)
void k_pv_f16(const float* __restrict__ S, const float* __restrict__ lse,
              const float* __restrict__ V, float* __restrict__ att) {
  int btc = blockIdx.x >> 2, nt = blockIdx.x & 3;
  const int n0 = nt * 128;
  const float* Sb = S + (long)btc * NN * NN + (long)n0 * NN;
  const float* lb = lse + btc * NN + n0;
  const float* Vb = V + (long)btc * NN * DD;
  float* attb = att + ((long)btc * NN + n0) * DD;

  __shared__ _Float16 Ph[128][72];   // P chunk [n][64 m + pad]
  __shared__ _Float16 Vt[128][72];   // V^T chunk [d][64 m + pad]

  const int tid = threadIdx.x;
  const int lane = tid & 63;
  const int wave = tid >> 6;
  const int frow = lane & 15;
  const int kgrp = lane >> 4;

  floatx4 acc[2][8];
  #pragma unroll
  for (int i = 0; i < 2; ++i)
    #pragma unroll
    for (int j = 0; j < 8; ++j)
      acc[i][j] = (floatx4){0.f, 0.f, 0.f, 0.f};

  for (int m0 = 0; m0 < NN; m0 += 64) {
    __syncthreads();
    for (int u = tid; u < 128 * 16; u += TPB) {
      int n = u >> 4, m4 = (u & 15) << 2;
      float l = lb[n];
      float4 s4 = *(const float4*)(Sb + (long)n * NN + m0 + m4);
      Ph[n][m4 + 0] = (_Float16)__expf(s4.x - l);
      Ph[n][m4 + 1] = (_Float16)__expf(s4.y - l);
      Ph[n][m4 + 2] = (_Float16)__expf(s4.z - l);
      Ph[n][m4 + 3] = (_Float16)__expf(s4.w - l);
    }
    for (int u = tid; u < 64 * 32; u += TPB) {
      int d4 = (u & 31) << 2, m = u >> 5;
      float4 v4 = *(const float4*)(Vb + (long)(m0 + m) * DD + d4);
      Vt[d4 + 0][m] = (_Float16)v4.x;
      Vt[d4 + 1][m] = (_Float16)v4.y;
      Vt[d4 + 2][m] = (_Float16)v4.z;
      Vt[d4 + 3][m] = (_Float16)v4.w;
    }
    __syncthreads();
    #pragma unroll
    for (int ks = 0; ks < 2; ++ks) {
      const int mk = ks * 32 + kgrp * 8;
      half8 a0 = *(const half8*)&Ph[wave * 32 + frow][mk];
      half8 a1 = *(const half8*)&Ph[wave * 32 + 16 + frow][mk];
      #pragma unroll
      for (int j = 0; j < 8; ++j) {
        half8 b = *(const half8*)&Vt[j * 16 + frow][mk];
        acc[0][j] = __builtin_amdgcn_mfma_f32_16x16x32_f16(a0, b, acc[0][j], 0, 0, 0);
        acc[1][j] = __builtin_amdgcn_mfma_f32_16x16x32_f16(a1, b, acc[1][j], 0, 0, 0);
      }
    }
  }
  #pragma unroll
  for (int i = 0; i < 2; ++i)
    #pragma unroll
    for (int j = 0; j < 8; ++j)
      #pragma unroll
      for (int r = 0; r < 4; ++r)
        attb[(long)(wave * 32 + i * 16 + kgrp * 4 + r) * DD + j * 16 + frow] = acc[i][j][r];
}

// ---- gather + Wo + residual + LN + FFN, all fp16 MFMA, LN in registers ----
// Layout identical to k_pv_f16: A=At[row][k], B=Bt[col][k],
// D: row_local = wave*32 + i*16 + kgrp*4 + r, col = j*16 + frow.
__global__ __launch_bounds__(TPB, 2)
void k_wo_ln_ffn(const float* __restrict__ att, const int* __restrict__ cp,
                 const float* __restrict__ Wo, const float* __restrict__ bo,
                 const float* __restrict__ xr,
                 const float* __restrict__ W1, const float* __restrict__ b1,
                 const float* __restrict__ W2, const float* __restrict__ b2,
                 float* __restrict__ out) {
  const int blk = blockIdx.x, btc = blk >> 2, rt = blk & 3;
  const int n0 = rt * 128;
  const long g0 = (long)btc * NN + n0;
  const float* attb = att + (long)btc * NN * DD;
  const int* cpb = cp + g0;

  __shared__ _Float16 At[128][136];
  __shared__ _Float16 Bt[128][136];

  const int tid = threadIdx.x;
  const int lane = tid & 63;
  const int wave = tid >> 6;
  const int frow = lane & 15;
  const int kgrp = lane >> 4;
  const int rbase = wave * 32;

  auto stage_wT = [&](const float* __restrict__ W) {
    for (int u = tid; u < 128 * 32; u += TPB) {
      int k = u >> 5, c4 = (u & 31) << 2;
      float4 v4 = *(const float4*)(W + (long)k * DD + c4);
      Bt[c4 + 0][k] = (_Float16)v4.x; Bt[c4 + 1][k] = (_Float16)v4.y;
      Bt[c4 + 2][k] = (_Float16)v4.z; Bt[c4 + 3][k] = (_Float16)v4.w;
    }
  };

  floatx4 acc[2][8];
  auto zero_acc = [&]() {
    #pragma unroll
    for (int i = 0; i < 2; ++i)
      #pragma unroll
      for (int j = 0; j < 8; ++j)
        acc[i][j] = (floatx4){0.f, 0.f, 0.f, 0.f};
  };
  auto mfma_tile = [&]() {
    #pragma unroll
    for (int ks = 0; ks < 4; ++ks) {
      const int mk = ks * 32 + kgrp * 8;
      half8 a0 = *(const half8*)&At[rbase + frow][mk];
      half8 a1 = *(const half8*)&At[rbase + 16 + frow][mk];
      #pragma unroll
      for (int j = 0; j < 8; ++j) {
        half8 b = *(const half8*)&Bt[j * 16 + frow][mk];
        acc[0][j] = __builtin_amdgcn_mfma_f32_16x16x32_f16(a0, b, acc[0][j], 0, 0, 0);
        acc[1][j] = __builtin_amdgcn_mfma_f32_16x16x32_f16(a1, b, acc[1][j], 0, 0, 0);
      }
    }
  };

  // ---- Phase A: gathered attended @ Wo ----
  for (int u = tid; u < 128 * 32; u += TPB) {
    int r = u >> 5, k4 = (u & 31) << 2;
    int src = cpb[r];
    float4 v4 = *(const float4*)(attb + (long)src * DD + k4);
    At[r][k4 + 0] = (_Float16)v4.x; At[r][k4 + 1] = (_Float16)v4.y;
    At[r][k4 + 2] = (_Float16)v4.z; At[r][k4 + 3] = (_Float16)v4.w;
  }
  stage_wT(Wo);
  __syncthreads();
  zero_acc();
  mfma_tile();
  __syncthreads();   // At/Bt reads done; safe to overwrite

  // ---- bias + residual + LayerNorm, in registers ----
  float v[2][8][4];
  #pragma unroll
  for (int i = 0; i < 2; ++i)
    #pragma unroll
    for (int j = 0; j < 8; ++j) {
      const int col = j * 16 + frow;
      const float bb = bo[col];
      #pragma unroll
      for (int r = 0; r < 4; ++r) {
        const long grow = g0 + rbase + i * 16 + kgrp * 4 + r;
        v[i][j][r] = acc[i][j][r] + bb + xr[grow * DD + col];
      }
    }
  #pragma unroll
  for (int i = 0; i < 2; ++i)
    #pragma unroll
    for (int r = 0; r < 4; ++r) {
      float s = 0.f, ss = 0.f;
      #pragma unroll
      for (int j = 0; j < 8; ++j) { float t = v[i][j][r]; s += t; ss += t * t; }
      #pragma unroll
      for (int d = 1; d < 16; d <<= 1) { s += __shfl_xor(s, d); ss += __shfl_xor(ss, d); }
      float mu = s * (1.f / 128.f);
      float var = ss * (1.f / 128.f) - mu * mu;
      float rs = rsqrtf(var + LNEPS);
      #pragma unroll
      for (int j = 0; j < 8; ++j) v[i][j][r] = (v[i][j][r] - mu) * rs;
    }
  // write normalized rows (fp16) into At (own wave's rows only) + stage W1^T
  #pragma unroll
  for (int i = 0; i < 2; ++i)
    #pragma unroll
    for (int j = 0; j < 8; ++j)
      #pragma unroll
      for (int r = 0; r < 4; ++r)
        At[rbase + i * 16 + kgrp * 4 + r][j * 16 + frow] = (_Float16)v[i][j][r];
  stage_wT(W1);
  __syncthreads();

  // ---- Phase B: H = relu(LN @ W1 + b1) ----
  zero_acc();
  mfma_tile();
  __syncthreads();
  #pragma unroll
  for (int i = 0; i < 2; ++i)
    #pragma unroll
    for (int j = 0; j < 8; ++j) {
      const int col = j * 16 + frow;
      const float bb = b1[col];
      #pragma unroll
      for (int r = 0; r < 4; ++r)
        At[rbase + i * 16 + kgrp * 4 + r][col] = (_Float16)fmaxf(acc[i][j][r] + bb, 0.f);
    }
  stage_wT(W2);
  __syncthreads();

  // ---- Phase C: out = H @ W2 + b2 ----
  zero_acc();
  mfma_tile();
  #pragma unroll
  for (int i = 0; i < 2; ++i)
    #pragma unroll
    for (int j = 0; j < 8; ++j) {
      const int col = j * 16 + frow;
      const float bb = b2[col];
      #pragma unroll
      for (int r = 0; r < 4; ++r) {
        const long grow = g0 + rbase + i * 16 + kgrp * 4 + r;
        out[grow * DD + col] = acc[i][j][r] + bb;
      }
    }
}

// ---------------- launch ----------------
extern "C" void kernel_launch(void* const* d_in, const int* in_sizes, int n_in,
                              void* d_out, int out_size, void* d_ws, size_t ws_size,
                              hipStream_t stream) {
  const float* x    = (const float*)d_in[0];
  const float* adj  = (const float*)d_in[1];
  const float* Wq   = (const float*)d_in[2];
  const float* bq   = (const float*)d_in[3];
  const float* Wk   = (const float*)d_in[4];
  const float* bk   = (const float*)d_in[5];
  const float* Wv   = (const float*)d_in[6];
  const float* bv   = (const float*)d_in[7];
  const float* Wo   = (const float*)d_in[8];
  const float* bo   = (const float*)d_in[9];
  const float* W1   = (const float*)d_in[10];
  const float* b1   = (const float*)d_in[11];
  const float* W2   = (const float*)d_in[12];
  const float* b2   = (const float*)d_in[13];
  float* out = (float*)d_out;
  (void)in_sizes; (void)n_in; (void)out_size;

  const size_t BT_ROWBYTES = (size_t)NN * DD * 4;                 // 262144
  const size_t per_bt = 5 * BT_ROWBYTES + (size_t)NN * NN * 4 + 2 * (size_t)NN * 4;
  static const int divs[] = {192, 96, 64, 48, 32, 24, 16, 12, 8, 6, 4, 3, 2, 1};
  int CH = 1;
  for (int i = 0; i < 14; ++i) {
    if ((size_t)divs[i] * per_bt + 8192 <= ws_size) { CH = divs[i]; break; }
  }

  char* ws = (char*)d_ws;
  size_t off = 0;
  auto alloc = [&](size_t bytes) -> void* {
    void* p = ws + off;
    off += (bytes + 255) & ~(size_t)255;
    return p;
  };
  float* xrc  = (float*)alloc((size_t)CH * BT_ROWBYTES);
  float* Qc   = (float*)alloc((size_t)CH * BT_ROWBYTES);
  float* Kc   = (float*)alloc((size_t)CH * BT_ROWBYTES);
  float* Vc   = (float*)alloc((size_t)CH * BT_ROWBYTES);
  float* attc = (float*)alloc((size_t)CH * BT_ROWBYTES);
  float* Sc   = (float*)alloc((size_t)CH * NN * NN * 4);
  float* lsec = (float*)alloc((size_t)CH * NN * 4);
  int*   cpc  = (int*)  alloc((size_t)CH * NN * 4);

  for (int c0 = 0; c0 < BTT; c0 += CH) {
    const size_t elemoff = (size_t)c0 * NN * DD;
    const float* xb  = x + elemoff;
    const float* ab  = adj + elemoff;
    float* outb = out + elemoff;
    int n4c = CH * NN * DD / 4;

    k_add<<<n4c / TPB, TPB, 0, stream>>>(xb, ab, xrc, n4c);

    k_gemm_bias<<<CH * 4, TPB, 0, stream>>>(xrc, Wq, bq, Qc);
    k_gemm_bias<<<CH * 4, TPB, 0, stream>>>(xrc, Wk, bk, Kc);
    k_gemm_bias<<<CH * 4, TPB, 0, stream>>>(xrc, Wv, bv, Vc);

    k_scores<<<CH * 16, TPB, 0, stream>>>(Qc, Kc, Sc);
    k_lse<<<CH * 128, TPB, 0, stream>>>(Sc, lsec);
    k_colargmax<<<CH * 8, TPB, 0, stream>>>(Sc, lsec, cpc);
    k_pv_f16<<<CH * 4, TPB, 0, stream>>>(Sc, lsec, Vc, attc);

    k_wo_ln_ffn<<<CH * 4, TPB, 0, stream>>>(attc, cpc, Wo, bo, xrc,
                                            W1, b1, W2, b2, outb);
  }
}

// Round 6
// 699.598 us; speedup vs baseline: 3.1522x; 1.1987x over previous
//
#include <hip/hip_runtime.h>
#include <math.h>

#define TPB 256
static constexpr int BTT = 192;    // B*T
static constexpr int NN  = 512;    // nodes
static constexpr int DD  = 128;    // feature dim
static constexpr float SCALE = 0.25f; // 1/sqrt(16)
static constexpr float LNEPS = 1e-5f;

typedef _Float16 half8 __attribute__((ext_vector_type(8)));
typedef short bf16x8 __attribute__((ext_vector_type(8)));
typedef float floatx4 __attribute__((ext_vector_type(4)));

// ---------------- elementwise add (chunk) ----------------
__global__ void k_add(const float* __restrict__ x, const float* __restrict__ g,
                      float* __restrict__ y, int n4) {
  int i = blockIdx.x * blockDim.x + threadIdx.x;
  if (i < n4) {
    const float4* xa = (const float4*)x;
    const float4* ga = (const float4*)g;
    float4 a = xa[i], b = ga[i];
    ((float4*)y)[i] = make_float4(a.x + b.x, a.y + b.y, a.z + b.z, a.w + b.w);
  }
}

// ---------------- shared fp32 GEMM micro-kernel pieces ----------------
__device__ __forceinline__ void stage_straight(float (*Bs)[132], const float* __restrict__ src,
                                               int ld, int tid) {
  #pragma unroll
  for (int u = tid; u < 1024; u += TPB) {
    int kk = u >> 5, c4 = (u & 31) << 2;
    *(float4*)&Bs[kk][c4] = *(const float4*)(src + (long)kk * ld + c4);
  }
}

__device__ __forceinline__ void stage_transposed(float (*As)[132], const float* __restrict__ src,
                                                 int ld, int tid) {
  #pragma unroll
  for (int u = tid; u < 1024; u += TPB) {
    int r = u >> 3, k4 = (u & 7) << 2;
    float4 v = *(const float4*)(src + (long)r * ld + k4);
    As[k4 + 0][r] = v.x; As[k4 + 1][r] = v.y; As[k4 + 2][r] = v.z; As[k4 + 3][r] = v.w;
  }
}

__device__ __forceinline__ void mt_compute(const float (*As)[132], const float (*Bs)[132],
                                           int r0, int c0a, float acc[8][8]) {
  #pragma unroll
  for (int kk = 0; kk < 32; ++kk) {
    float a[8], b[8];
    *(float4*)&a[0] = *(const float4*)&As[kk][r0];
    *(float4*)&a[4] = *(const float4*)&As[kk][r0 + 4];
    *(float4*)&b[0] = *(const float4*)&Bs[kk][c0a];
    *(float4*)&b[4] = *(const float4*)&Bs[kk][c0a + 64];
    #pragma unroll
    for (int i = 0; i < 8; ++i)
      #pragma unroll
      for (int j = 0; j < 8; ++j)
        acc[i][j] = fmaf(a[i], b[j], acc[i][j]);
  }
}

// ---------------- GEMM + bias (fp32 — Q,K: argmax-critical, bitwise stable) ----------------
__global__ __launch_bounds__(TPB, 2)
void k_gemm_bias(const float* __restrict__ A, const float* __restrict__ W,
                 const float* __restrict__ bias, float* __restrict__ C) {
  __shared__ float As[32][132];
  __shared__ float Bs[32][132];
  const int tid = threadIdx.x;
  const int tr = tid >> 4, tc = tid & 15;
  const int r0 = tr * 8, c0a = tc * 4;
  const long rowblk = (long)blockIdx.x * 128;
  float acc[8][8] = {};
  for (int k0 = 0; k0 < 128; k0 += 32) {
    stage_transposed(As, A + rowblk * 128 + k0, 128, tid);
    stage_straight(Bs, W + (long)k0 * 128, 128, tid);
    __syncthreads();
    mt_compute(As, Bs, r0, c0a, acc);
    __syncthreads();
  }
  float4 blo = *(const float4*)(bias + c0a);
  float4 bhi = *(const float4*)(bias + c0a + 64);
  #pragma unroll
  for (int i = 0; i < 8; ++i) {
    float* crow = C + (rowblk + r0 + i) * 128;
    *(float4*)(crow + c0a) = make_float4(acc[i][0] + blo.x, acc[i][1] + blo.y,
                                         acc[i][2] + blo.z, acc[i][3] + blo.w);
    *(float4*)(crow + c0a + 64) = make_float4(acc[i][4] + bhi.x, acc[i][5] + bhi.y,
                                              acc[i][6] + bhi.z, acc[i][7] + bhi.w);
  }
}

// ---------------- GEMM + bias via fp16 MFMA (V: smooth path) ----------------
__global__ __launch_bounds__(TPB, 2)
void k_gemm_bias_f16(const float* __restrict__ A, const float* __restrict__ W,
                     const float* __restrict__ bias, float* __restrict__ C) {
  __shared__ _Float16 At[128][136];
  __shared__ _Float16 Bt[128][136];
  const int tid = threadIdx.x;
  const int lane = tid & 63;
  const int wave = tid >> 6;
  const int frow = lane & 15;
  const int kgrp = lane >> 4;
  const int rbase = wave * 32;
  const long rowblk = (long)blockIdx.x * 128;

  for (int u = tid; u < 128 * 32; u += TPB) {
    int r = u >> 5, k4 = (u & 31) << 2;
    float4 v4 = *(const float4*)(A + (rowblk + r) * DD + k4);
    At[r][k4 + 0] = (_Float16)v4.x; At[r][k4 + 1] = (_Float16)v4.y;
    At[r][k4 + 2] = (_Float16)v4.z; At[r][k4 + 3] = (_Float16)v4.w;
  }
  for (int u = tid; u < 128 * 32; u += TPB) {
    int k = u >> 5, c4 = (u & 31) << 2;
    float4 v4 = *(const float4*)(W + (long)k * DD + c4);
    Bt[c4 + 0][k] = (_Float16)v4.x; Bt[c4 + 1][k] = (_Float16)v4.y;
    Bt[c4 + 2][k] = (_Float16)v4.z; Bt[c4 + 3][k] = (_Float16)v4.w;
  }
  __syncthreads();

  floatx4 acc[2][8];
  #pragma unroll
  for (int i = 0; i < 2; ++i)
    #pragma unroll
    for (int j = 0; j < 8; ++j)
      acc[i][j] = (floatx4){0.f, 0.f, 0.f, 0.f};
  #pragma unroll
  for (int ks = 0; ks < 4; ++ks) {
    const int mk = ks * 32 + kgrp * 8;
    half8 a0 = *(const half8*)&At[rbase + frow][mk];
    half8 a1 = *(const half8*)&At[rbase + 16 + frow][mk];
    #pragma unroll
    for (int j = 0; j < 8; ++j) {
      half8 b = *(const half8*)&Bt[j * 16 + frow][mk];
      acc[0][j] = __builtin_amdgcn_mfma_f32_16x16x32_f16(a0, b, acc[0][j], 0, 0, 0);
      acc[1][j] = __builtin_amdgcn_mfma_f32_16x16x32_f16(a1, b, acc[1][j], 0, 0, 0);
    }
  }
  #pragma unroll
  for (int i = 0; i < 2; ++i)
    #pragma unroll
    for (int j = 0; j < 8; ++j) {
      const int col = j * 16 + frow;
      const float bb = bias[col];
      #pragma unroll
      for (int r = 0; r < 4; ++r)
        C[(rowblk + rbase + i * 16 + kgrp * 4 + r) * DD + col] = acc[i][j][r] + bb;
    }
}

// ---------------- exact 3-limb bf16 split (truncation; q == h+m+l exactly) ----------------
__device__ __forceinline__ void split3(float q, unsigned short& h, unsigned short& m,
                                       unsigned short& l) {
  unsigned uh = __float_as_uint(q) & 0xFFFF0000u;
  float fh = __uint_as_float(uh);
  float r1 = q - fh;                       // exact
  unsigned um = __float_as_uint(r1) & 0xFFFF0000u;
  float fm = __uint_as_float(um);
  float r2 = r1 - fm;                      // exact, fits in bf16
  unsigned ul = __float_as_uint(r2) & 0xFFFF0000u;
  h = (unsigned short)(uh >> 16);
  m = (unsigned short)(um >> 16);
  l = (unsigned short)(ul >> 16);
}

// ---------------- scores via bf16x3 MFMA: S = Q·K^T * 0.25, ~fp32-accurate ----------------
// 6 limb products (hh,hm,mh,hl,lh,mm), accumulated small->large into fp32 acc.
__global__ __launch_bounds__(TPB, 2)
void k_scores_mfma(const float* __restrict__ Q, const float* __restrict__ K,
                   float* __restrict__ S) {
  int blk = blockIdx.x;            // btc*16 + rt*4 + ct
  int btc = blk >> 4, rt = (blk >> 2) & 3, ct = blk & 3;
  const float* Qb = Q + (long)btc * NN * DD + (long)rt * 128 * DD;
  const float* Kb = K + (long)btc * NN * DD + (long)ct * 128 * DD;
  float* Sb = S + (long)btc * NN * NN + (long)rt * 128 * NN + ct * 128;

  __shared__ unsigned short Qh[128][40], Qm[128][40], Ql[128][40];
  __shared__ unsigned short Kh[128][40], Km[128][40], Kl[128][40];

  const int tid = threadIdx.x;
  const int lane = tid & 63;
  const int wave = tid >> 6;
  const int frow = lane & 15;
  const int kgrp = lane >> 4;
  const int rbase = wave * 32;

  floatx4 acc[2][8];
  #pragma unroll
  for (int i = 0; i < 2; ++i)
    #pragma unroll
    for (int j = 0; j < 8; ++j)
      acc[i][j] = (floatx4){0.f, 0.f, 0.f, 0.f};

  for (int k0 = 0; k0 < 128; k0 += 32) {
    __syncthreads();   // previous iteration's reads done
    // stage + split: 2 matrices x 128 rows x 32 k
    #pragma unroll
    for (int u = tid; u < 2048; u += TPB) {
      int mat = u >> 10, rem = u & 1023;
      int row = rem >> 3, k4 = (rem & 7) << 2;
      const float* src = (mat ? Kb : Qb) + (long)row * DD + k0 + k4;
      float4 v = *(const float4*)src;
      unsigned short h0, m0, l0, h1, m1, l1, h2, m2, l2, h3, m3, l3;
      split3(v.x, h0, m0, l0); split3(v.y, h1, m1, l1);
      split3(v.z, h2, m2, l2); split3(v.w, h3, m3, l3);
      if (mat == 0) {
        Qh[row][k4] = h0; Qh[row][k4+1] = h1; Qh[row][k4+2] = h2; Qh[row][k4+3] = h3;
        Qm[row][k4] = m0; Qm[row][k4+1] = m1; Qm[row][k4+2] = m2; Qm[row][k4+3] = m3;
        Ql[row][k4] = l0; Ql[row][k4+1] = l1; Ql[row][k4+2] = l2; Ql[row][k4+3] = l3;
      } else {
        Kh[row][k4] = h0; Kh[row][k4+1] = h1; Kh[row][k4+2] = h2; Kh[row][k4+3] = h3;
        Km[row][k4] = m0; Km[row][k4+1] = m1; Km[row][k4+2] = m2; Km[row][k4+3] = m3;
        Kl[row][k4] = l0; Kl[row][k4+1] = l1; Kl[row][k4+2] = l2; Kl[row][k4+3] = l3;
      }
    }
    __syncthreads();

    const int mk = kgrp * 8;
    bf16x8 aH0 = *(const bf16x8*)&Qh[rbase + frow][mk];
    bf16x8 aH1 = *(const bf16x8*)&Qh[rbase + 16 + frow][mk];
    bf16x8 aM0 = *(const bf16x8*)&Qm[rbase + frow][mk];
    bf16x8 aM1 = *(const bf16x8*)&Qm[rbase + 16 + frow][mk];
    bf16x8 aL0 = *(const bf16x8*)&Ql[rbase + frow][mk];
    bf16x8 aL1 = *(const bf16x8*)&Ql[rbase + 16 + frow][mk];
    #pragma unroll
    for (int j = 0; j < 8; ++j) {
      bf16x8 bH = *(const bf16x8*)&Kh[j * 16 + frow][mk];
      bf16x8 bM = *(const bf16x8*)&Km[j * 16 + frow][mk];
      bf16x8 bL = *(const bf16x8*)&Kl[j * 16 + frow][mk];
      // small -> large
      acc[0][j] = __builtin_amdgcn_mfma_f32_16x16x32_bf16(aM0, bM, acc[0][j], 0, 0, 0);
      acc[1][j] = __builtin_amdgcn_mfma_f32_16x16x32_bf16(aM1, bM, acc[1][j], 0, 0, 0);
      acc[0][j] = __builtin_amdgcn_mfma_f32_16x16x32_bf16(aH0, bL, acc[0][j], 0, 0, 0);
      acc[1][j] = __builtin_amdgcn_mfma_f32_16x16x32_bf16(aH1, bL, acc[1][j], 0, 0, 0);
      acc[0][j] = __builtin_amdgcn_mfma_f32_16x16x32_bf16(aL0, bH, acc[0][j], 0, 0, 0);
      acc[1][j] = __builtin_amdgcn_mfma_f32_16x16x32_bf16(aL1, bH, acc[1][j], 0, 0, 0);
      acc[0][j] = __builtin_amdgcn_mfma_f32_16x16x32_bf16(aH0, bM, acc[0][j], 0, 0, 0);
      acc[1][j] = __builtin_amdgcn_mfma_f32_16x16x32_bf16(aH1, bM, acc[1][j], 0, 0, 0);
      acc[0][j] = __builtin_amdgcn_mfma_f32_16x16x32_bf16(aM0, bH, acc[0][j], 0, 0, 0);
      acc[1][j] = __builtin_amdgcn_mfma_f32_16x16x32_bf16(aM1, bH, acc[1][j], 0, 0, 0);
      acc[0][j] = __builtin_amdgcn_mfma_f32_16x16x32_bf16(aH0, bH, acc[0][j], 0, 0, 0);
      acc[1][j] = __builtin_amdgcn_mfma_f32_16x16x32_bf16(aH1, bH, acc[1][j], 0, 0, 0);
    }
  }
  #pragma unroll
  for (int i = 0; i < 2; ++i)
    #pragma unroll
    for (int j = 0; j < 8; ++j)
      #pragma unroll
      for (int r = 0; r < 4; ++r)
        Sb[(long)(rbase + i * 16 + kgrp * 4 + r) * NN + j * 16 + frow] =
            acc[i][j][r] * SCALE;
}

// ---------------- row LSE over 512 (unchanged algorithm) ----------------
__global__ void k_lse(const float* __restrict__ S, float* __restrict__ lse) {
  int w = threadIdx.x >> 6, lane = threadIdx.x & 63;
  long row = (long)blockIdx.x * 4 + w;
  const float4* p = (const float4*)(S + row * NN);
  float4 a = p[lane], b = p[lane + 64];
  float m = fmaxf(fmaxf(fmaxf(a.x, a.y), fmaxf(a.z, a.w)),
                  fmaxf(fmaxf(b.x, b.y), fmaxf(b.z, b.w)));
  #pragma unroll
  for (int d = 1; d < 64; d <<= 1) m = fmaxf(m, __shfl_xor(m, d));
  float s = expf(a.x - m) + expf(a.y - m) + expf(a.z - m) + expf(a.w - m)
          + expf(b.x - m) + expf(b.y - m) + expf(b.z - m) + expf(b.w - m);
  #pragma unroll
  for (int d = 1; d < 64; d <<= 1) s += __shfl_xor(s, d);
  if (lane == 0) lse[row] = m + logf(s);
}

// ---------------- column argmax, 4-way split over rows (unchanged) ----------------
__global__ __launch_bounds__(TPB)
void k_colargmax(const float* __restrict__ S, const float* __restrict__ lse,
                 int* __restrict__ cp) {
  int btc = blockIdx.x >> 3, cg = blockIdx.x & 7;
  int c = threadIdx.x & 63;
  int col = cg * 64 + c;
  int seg = threadIdx.x >> 6;
  const float* Sb = S + (long)btc * NN * NN;
  const float* lb = lse + btc * NN;
  float best = -3.4e38f;
  int bi = seg * 128;
  for (int n = seg * 128; n < seg * 128 + 128; ++n) {
    float v = Sb[(long)n * NN + col] - lb[n];
    if (v > best) { best = v; bi = n; }
  }
  __shared__ float bv[4][64];
  __shared__ int bidx[4][64];
  bv[seg][c] = best; bidx[seg][c] = bi;
  __syncthreads();
  if (seg == 0) {
    #pragma unroll
    for (int s = 1; s < 4; ++s) {
      float v2 = bv[s][c];
      if (v2 > best) { best = v2; bi = bidx[s][c]; }
    }
    cp[btc * NN + col] = bi;
  }
}

// ---------------- PV via fp16 MFMA (unchanged) ----------------
__global__ __launch_bounds__(TPB, 2)
void k_pv_f16(const float* __restrict__ S, const float* __restrict__ lse,
              const float* __restrict__ V, float* __restrict__ att) {
  int btc = blockIdx.x >> 2, nt = blockIdx.x & 3;
  const int n0 = nt * 128;
  const float* Sb = S + (long)btc * NN * NN + (long)n0 * NN;
  const float* lb = lse + btc * NN + n0;
  const float* Vb = V + (long)btc * NN * DD;
  float* attb = att + ((long)btc * NN + n0) * DD;

  __shared__ _Float16 Ph[128][72];
  __shared__ _Float16 Vt[128][72];

  const int tid = threadIdx.x;
  const int lane = tid & 63;
  const int wave = tid >> 6;
  const int frow = lane & 15;
  const int kgrp = lane >> 4;

  floatx4 acc[2][8];
  #pragma unroll
  for (int i = 0; i < 2; ++i)
    #pragma unroll
    for (int j = 0; j < 8; ++j)
      acc[i][j] = (floatx4){0.f, 0.f, 0.f, 0.f};

  for (int m0 = 0; m0 < NN; m0 += 64) {
    __syncthreads();
    for (int u = tid; u < 128 * 16; u += TPB) {
      int n = u >> 4, m4 = (u & 15) << 2;
      float l = lb[n];
      float4 s4 = *(const float4*)(Sb + (long)n * NN + m0 + m4);
      Ph[n][m4 + 0] = (_Float16)__expf(s4.x - l);
      Ph[n][m4 + 1] = (_Float16)__expf(s4.y - l);
      Ph[n][m4 + 2] = (_Float16)__expf(s4.z - l);
      Ph[n][m4 + 3] = (_Float16)__expf(s4.w - l);
    }
    for (int u = tid; u < 64 * 32; u += TPB) {
      int d4 = (u & 31) << 2, m = u >> 5;
      float4 v4 = *(const float4*)(Vb + (long)(m0 + m) * DD + d4);
      Vt[d4 + 0][m] = (_Float16)v4.x;
      Vt[d4 + 1][m] = (_Float16)v4.y;
      Vt[d4 + 2][m] = (_Float16)v4.z;
      Vt[d4 + 3][m] = (_Float16)v4.w;
    }
    __syncthreads();
    #pragma unroll
    for (int ks = 0; ks < 2; ++ks) {
      const int mk = ks * 32 + kgrp * 8;
      half8 a0 = *(const half8*)&Ph[wave * 32 + frow][mk];
      half8 a1 = *(const half8*)&Ph[wave * 32 + 16 + frow][mk];
      #pragma unroll
      for (int j = 0; j < 8; ++j) {
        half8 b = *(const half8*)&Vt[j * 16 + frow][mk];
        acc[0][j] = __builtin_amdgcn_mfma_f32_16x16x32_f16(a0, b, acc[0][j], 0, 0, 0);
        acc[1][j] = __builtin_amdgcn_mfma_f32_16x16x32_f16(a1, b, acc[1][j], 0, 0, 0);
      }
    }
  }
  #pragma unroll
  for (int i = 0; i < 2; ++i)
    #pragma unroll
    for (int j = 0; j < 8; ++j)
      #pragma unroll
      for (int r = 0; r < 4; ++r)
        attb[(long)(wave * 32 + i * 16 + kgrp * 4 + r) * DD + j * 16 + frow] = acc[i][j][r];
}

// ---- gather + Wo + residual + LN + FFN, fp16 MFMA (unchanged) ----
__global__ __launch_bounds__(TPB, 2)
void k_wo_ln_ffn(const float* __restrict__ att, const int* __restrict__ cp,
                 const float* __restrict__ Wo, const float* __restrict__ bo,
                 const float* __restrict__ xr,
                 const float* __restrict__ W1, const float* __restrict__ b1,
                 const float* __restrict__ W2, const float* __restrict__ b2,
                 float* __restrict__ out) {
  const int blk = blockIdx.x, btc = blk >> 2, rt = blk & 3;
  const int n0 = rt * 128;
  const long g0 = (long)btc * NN + n0;
  const float* attb = att + (long)btc * NN * DD;
  const int* cpb = cp + g0;

  __shared__ _Float16 At[128][136];
  __shared__ _Float16 Bt[128][136];

  const int tid = threadIdx.x;
  const int lane = tid & 63;
  const int wave = tid >> 6;
  const int frow = lane & 15;
  const int kgrp = lane >> 4;
  const int rbase = wave * 32;

  auto stage_wT = [&](const float* __restrict__ W) {
    for (int u = tid; u < 128 * 32; u += TPB) {
      int k = u >> 5, c4 = (u & 31) << 2;
      float4 v4 = *(const float4*)(W + (long)k * DD + c4);
      Bt[c4 + 0][k] = (_Float16)v4.x; Bt[c4 + 1][k] = (_Float16)v4.y;
      Bt[c4 + 2][k] = (_Float16)v4.z; Bt[c4 + 3][k] = (_Float16)v4.w;
    }
  };

  floatx4 acc[2][8];
  auto zero_acc = [&]() {
    #pragma unroll
    for (int i = 0; i < 2; ++i)
      #pragma unroll
      for (int j = 0; j < 8; ++j)
        acc[i][j] = (floatx4){0.f, 0.f, 0.f, 0.f};
  };
  auto mfma_tile = [&]() {
    #pragma unroll
    for (int ks = 0; ks < 4; ++ks) {
      const int mk = ks * 32 + kgrp * 8;
      half8 a0 = *(const half8*)&At[rbase + frow][mk];
      half8 a1 = *(const half8*)&At[rbase + 16 + frow][mk];
      #pragma unroll
      for (int j = 0; j < 8; ++j) {
        half8 b = *(const half8*)&Bt[j * 16 + frow][mk];
        acc[0][j] = __builtin_amdgcn_mfma_f32_16x16x32_f16(a0, b, acc[0][j], 0, 0, 0);
        acc[1][j] = __builtin_amdgcn_mfma_f32_16x16x32_f16(a1, b, acc[1][j], 0, 0, 0);
      }
    }
  };

  // Phase A: gathered attended @ Wo
  for (int u = tid; u < 128 * 32; u += TPB) {
    int r = u >> 5, k4 = (u & 31) << 2;
    int src = cpb[r];
    float4 v4 = *(const float4*)(attb + (long)src * DD + k4);
    At[r][k4 + 0] = (_Float16)v4.x; At[r][k4 + 1] = (_Float16)v4.y;
    At[r][k4 + 2] = (_Float16)v4.z; At[r][k4 + 3] = (_Float16)v4.w;
  }
  stage_wT(Wo);
  __syncthreads();
  zero_acc();
  mfma_tile();
  __syncthreads();

  // bias + residual + LayerNorm in registers
  float v[2][8][4];
  #pragma unroll
  for (int i = 0; i < 2; ++i)
    #pragma unroll
    for (int j = 0; j < 8; ++j) {
      const int col = j * 16 + frow;
      const float bb = bo[col];
      #pragma unroll
      for (int r = 0; r < 4; ++r) {
        const long grow = g0 + rbase + i * 16 + kgrp * 4 + r;
        v[i][j][r] = acc[i][j][r] + bb + xr[grow * DD + col];
      }
    }
  #pragma unroll
  for (int i = 0; i < 2; ++i)
    #pragma unroll
    for (int r = 0; r < 4; ++r) {
      float s = 0.f, ss = 0.f;
      #pragma unroll
      for (int j = 0; j < 8; ++j) { float t = v[i][j][r]; s += t; ss += t * t; }
      #pragma unroll
      for (int d = 1; d < 16; d <<= 1) { s += __shfl_xor(s, d); ss += __shfl_xor(ss, d); }
      float mu = s * (1.f / 128.f);
      float var = ss * (1.f / 128.f) - mu * mu;
      float rs = rsqrtf(var + LNEPS);
      #pragma unroll
      for (int j = 0; j < 8; ++j) v[i][j][r] = (v[i][j][r] - mu) * rs;
    }
  #pragma unroll
  for (int i = 0; i < 2; ++i)
    #pragma unroll
    for (int j = 0; j < 8; ++j)
      #pragma unroll
      for (int r = 0; r < 4; ++r)
        At[rbase + i * 16 + kgrp * 4 + r][j * 16 + frow] = (_Float16)v[i][j][r];
  stage_wT(W1);
  __syncthreads();

  // Phase B: H = relu(LN @ W1 + b1)
  zero_acc();
  mfma_tile();
  __syncthreads();
  #pragma unroll
  for (int i = 0; i < 2; ++i)
    #pragma unroll
    for (int j = 0; j < 8; ++j) {
      const int col = j * 16 + frow;
      const float bb = b1[col];
      #pragma unroll
      for (int r = 0; r < 4; ++r)
        At[rbase + i * 16 + kgrp * 4 + r][col] = (_Float16)fmaxf(acc[i][j][r] + bb, 0.f);
    }
  stage_wT(W2);
  __syncthreads();

  // Phase C: out = H @ W2 + b2
  zero_acc();
  mfma_tile();
  #pragma unroll
  for (int i = 0; i < 2; ++i)
    #pragma unroll
    for (int j = 0; j < 8; ++j) {
      const int col = j * 16 + frow;
      const float bb = b2[col];
      #pragma unroll
      for (int r = 0; r < 4; ++r) {
        const long grow = g0 + rbase + i * 16 + kgrp * 4 + r;
        out[grow * DD + col] = acc[i][j][r] + bb;
      }
    }
}

// ---------------- launch ----------------
extern "C" void kernel_launch(void* const* d_in, const int* in_sizes, int n_in,
                              void* d_out, int out_size, void* d_ws, size_t ws_size,
                              hipStream_t stream) {
  const float* x    = (const float*)d_in[0];
  const float* adj  = (const float*)d_in[1];
  const float* Wq   = (const float*)d_in[2];
  const float* bq   = (const float*)d_in[3];
  const float* Wk   = (const float*)d_in[4];
  const float* bk   = (const float*)d_in[5];
  const float* Wv   = (const float*)d_in[6];
  const float* bv   = (const float*)d_in[7];
  const float* Wo   = (const float*)d_in[8];
  const float* bo   = (const float*)d_in[9];
  const float* W1   = (const float*)d_in[10];
  const float* b1   = (const float*)d_in[11];
  const float* W2   = (const float*)d_in[12];
  const float* b2   = (const float*)d_in[13];
  float* out = (float*)d_out;
  (void)in_sizes; (void)n_in; (void)out_size;

  const size_t BT_ROWBYTES = (size_t)NN * DD * 4;                 // 262144
  const size_t per_bt = 5 * BT_ROWBYTES + (size_t)NN * NN * 4 + 2 * (size_t)NN * 4;
  static const int divs[] = {192, 96, 64, 48, 32, 24, 16, 12, 8, 6, 4, 3, 2, 1};
  int CH = 1;
  for (int i = 0; i < 14; ++i) {
    if ((size_t)divs[i] * per_bt + 8192 <= ws_size) { CH = divs[i]; break; }
  }

  char* ws = (char*)d_ws;
  size_t off = 0;
  auto alloc = [&](size_t bytes) -> void* {
    void* p = ws + off;
    off += (bytes + 255) & ~(size_t)255;
    return p;
  };
  float* xrc  = (float*)alloc((size_t)CH * BT_ROWBYTES);
  float* Qc   = (float*)alloc((size_t)CH * BT_ROWBYTES);
  float* Kc   = (float*)alloc((size_t)CH * BT_ROWBYTES);
  float* Vc   = (float*)alloc((size_t)CH * BT_ROWBYTES);
  float* attc = (float*)alloc((size_t)CH * BT_ROWBYTES);
  float* Sc   = (float*)alloc((size_t)CH * NN * NN * 4);
  float* lsec = (float*)alloc((size_t)CH * NN * 4);
  int*   cpc  = (int*)  alloc((size_t)CH * NN * 4);

  for (int c0 = 0; c0 < BTT; c0 += CH) {
    const size_t elemoff = (size_t)c0 * NN * DD;
    const float* xb  = x + elemoff;
    const float* ab  = adj + elemoff;
    float* outb = out + elemoff;
    int n4c = CH * NN * DD / 4;

    k_add<<<n4c / TPB, TPB, 0, stream>>>(xb, ab, xrc, n4c);

    k_gemm_bias<<<CH * 4, TPB, 0, stream>>>(xrc, Wq, bq, Qc);
    k_gemm_bias<<<CH * 4, TPB, 0, stream>>>(xrc, Wk, bk, Kc);
    k_gemm_bias_f16<<<CH * 4, TPB, 0, stream>>>(xrc, Wv, bv, Vc);

    k_scores_mfma<<<CH * 16, TPB, 0, stream>>>(Qc, Kc, Sc);
    k_lse<<<CH * 128, TPB, 0, stream>>>(Sc, lsec);
    k_colargmax<<<CH * 8, TPB, 0, stream>>>(Sc, lsec, cpc);
    k_pv_f16<<<CH * 4, TPB, 0, stream>>>(Sc, lsec, Vc, attc);

    k_wo_ln_ffn<<<CH * 4, TPB, 0, stream>>>(attc, cpc, Wo, bo, xrc,
                                            W1, b1, W2, b2, outb);
  }
}

// Round 7
// 634.185 us; speedup vs baseline: 3.4774x; 1.1031x over previous
//
#include <hip/hip_runtime.h>
#include <math.h>

#define TPB 256
static constexpr int BTT = 192;    // B*T
static constexpr int NN  = 512;    // nodes
static constexpr int DD  = 128;    // feature dim
static constexpr float SCALE = 0.25f; // 1/sqrt(16)
static constexpr float LNEPS = 1e-5f;

typedef _Float16 half8 __attribute__((ext_vector_type(8)));
typedef short bf16x8 __attribute__((ext_vector_type(8)));
typedef float floatx4 __attribute__((ext_vector_type(4)));

// ---------------- elementwise add (chunk) ----------------
__global__ void k_add(const float* __restrict__ x, const float* __restrict__ g,
                      float* __restrict__ y, int n4) {
  int i = blockIdx.x * blockDim.x + threadIdx.x;
  if (i < n4) {
    const float4* xa = (const float4*)x;
    const float4* ga = (const float4*)g;
    float4 a = xa[i], b = ga[i];
    ((float4*)y)[i] = make_float4(a.x + b.x, a.y + b.y, a.z + b.z, a.w + b.w);
  }
}

// ---------------- shared fp32 GEMM micro-kernel pieces ----------------
__device__ __forceinline__ void stage_straight(float (*Bs)[132], const float* __restrict__ src,
                                               int ld, int tid) {
  #pragma unroll
  for (int u = tid; u < 1024; u += TPB) {
    int kk = u >> 5, c4 = (u & 31) << 2;
    *(float4*)&Bs[kk][c4] = *(const float4*)(src + (long)kk * ld + c4);
  }
}

__device__ __forceinline__ void stage_transposed(float (*As)[132], const float* __restrict__ src,
                                                 int ld, int tid) {
  #pragma unroll
  for (int u = tid; u < 1024; u += TPB) {
    int r = u >> 3, k4 = (u & 7) << 2;
    float4 v = *(const float4*)(src + (long)r * ld + k4);
    As[k4 + 0][r] = v.x; As[k4 + 1][r] = v.y; As[k4 + 2][r] = v.z; As[k4 + 3][r] = v.w;
  }
}

__device__ __forceinline__ void mt_compute(const float (*As)[132], const float (*Bs)[132],
                                           int r0, int c0a, float acc[8][8]) {
  #pragma unroll
  for (int kk = 0; kk < 32; ++kk) {
    float a[8], b[8];
    *(float4*)&a[0] = *(const float4*)&As[kk][r0];
    *(float4*)&a[4] = *(const float4*)&As[kk][r0 + 4];
    *(float4*)&b[0] = *(const float4*)&Bs[kk][c0a];
    *(float4*)&b[4] = *(const float4*)&Bs[kk][c0a + 64];
    #pragma unroll
    for (int i = 0; i < 8; ++i)
      #pragma unroll
      for (int j = 0; j < 8; ++j)
        acc[i][j] = fmaf(a[i], b[j], acc[i][j]);
  }
}

// ---------------- GEMM + bias (fp32 — Q,K: argmax-critical, bitwise stable) ----------------
__global__ __launch_bounds__(TPB, 2)
void k_gemm_bias(const float* __restrict__ A, const float* __restrict__ W,
                 const float* __restrict__ bias, float* __restrict__ C) {
  __shared__ float As[32][132];
  __shared__ float Bs[32][132];
  const int tid = threadIdx.x;
  const int tr = tid >> 4, tc = tid & 15;
  const int r0 = tr * 8, c0a = tc * 4;
  const long rowblk = (long)blockIdx.x * 128;
  float acc[8][8] = {};
  for (int k0 = 0; k0 < 128; k0 += 32) {
    stage_transposed(As, A + rowblk * 128 + k0, 128, tid);
    stage_straight(Bs, W + (long)k0 * 128, 128, tid);
    __syncthreads();
    mt_compute(As, Bs, r0, c0a, acc);
    __syncthreads();
  }
  float4 blo = *(const float4*)(bias + c0a);
  float4 bhi = *(const float4*)(bias + c0a + 64);
  #pragma unroll
  for (int i = 0; i < 8; ++i) {
    float* crow = C + (rowblk + r0 + i) * 128;
    *(float4*)(crow + c0a) = make_float4(acc[i][0] + blo.x, acc[i][1] + blo.y,
                                         acc[i][2] + blo.z, acc[i][3] + blo.w);
    *(float4*)(crow + c0a + 64) = make_float4(acc[i][4] + bhi.x, acc[i][5] + bhi.y,
                                              acc[i][6] + bhi.z, acc[i][7] + bhi.w);
  }
}

// ---------------- GEMM + bias via fp16 MFMA (V: smooth path) ----------------
__global__ __launch_bounds__(TPB, 2)
void k_gemm_bias_f16(const float* __restrict__ A, const float* __restrict__ W,
                     const float* __restrict__ bias, float* __restrict__ C) {
  __shared__ _Float16 At[128][136];
  __shared__ _Float16 Bt[128][136];
  const int tid = threadIdx.x;
  const int lane = tid & 63;
  const int wave = tid >> 6;
  const int frow = lane & 15;
  const int kgrp = lane >> 4;
  const int rbase = wave * 32;
  const long rowblk = (long)blockIdx.x * 128;

  for (int u = tid; u < 128 * 32; u += TPB) {
    int r = u >> 5, k4 = (u & 31) << 2;
    float4 v4 = *(const float4*)(A + (rowblk + r) * DD + k4);
    At[r][k4 + 0] = (_Float16)v4.x; At[r][k4 + 1] = (_Float16)v4.y;
    At[r][k4 + 2] = (_Float16)v4.z; At[r][k4 + 3] = (_Float16)v4.w;
  }
  for (int u = tid; u < 128 * 32; u += TPB) {
    int k = u >> 5, c4 = (u & 31) << 2;
    float4 v4 = *(const float4*)(W + (long)k * DD + c4);
    Bt[c4 + 0][k] = (_Float16)v4.x; Bt[c4 + 1][k] = (_Float16)v4.y;
    Bt[c4 + 2][k] = (_Float16)v4.z; Bt[c4 + 3][k] = (_Float16)v4.w;
  }
  __syncthreads();

  floatx4 acc[2][8];
  #pragma unroll
  for (int i = 0; i < 2; ++i)
    #pragma unroll
    for (int j = 0; j < 8; ++j)
      acc[i][j] = (floatx4){0.f, 0.f, 0.f, 0.f};
  #pragma unroll
  for (int ks = 0; ks < 4; ++ks) {
    const int mk = ks * 32 + kgrp * 8;
    half8 a0 = *(const half8*)&At[rbase + frow][mk];
    half8 a1 = *(const half8*)&At[rbase + 16 + frow][mk];
    #pragma unroll
    for (int j = 0; j < 8; ++j) {
      half8 b = *(const half8*)&Bt[j * 16 + frow][mk];
      acc[0][j] = __builtin_amdgcn_mfma_f32_16x16x32_f16(a0, b, acc[0][j], 0, 0, 0);
      acc[1][j] = __builtin_amdgcn_mfma_f32_16x16x32_f16(a1, b, acc[1][j], 0, 0, 0);
    }
  }
  #pragma unroll
  for (int i = 0; i < 2; ++i)
    #pragma unroll
    for (int j = 0; j < 8; ++j) {
      const int col = j * 16 + frow;
      const float bb = bias[col];
      #pragma unroll
      for (int r = 0; r < 4; ++r)
        C[(rowblk + rbase + i * 16 + kgrp * 4 + r) * DD + col] = acc[i][j][r] + bb;
    }
}

// ---------------- exact 3-limb bf16 split (truncation; q == h+m+l exactly) ----------------
__device__ __forceinline__ void split3(float q, unsigned short& h, unsigned short& m,
                                       unsigned short& l) {
  unsigned uh = __float_as_uint(q) & 0xFFFF0000u;
  float fh = __uint_as_float(uh);
  float r1 = q - fh;                       // exact
  unsigned um = __float_as_uint(r1) & 0xFFFF0000u;
  float fm = __uint_as_float(um);
  float r2 = r1 - fm;                      // exact, fits in bf16
  unsigned ul = __float_as_uint(r2) & 0xFFFF0000u;
  h = (unsigned short)(uh >> 16);
  m = (unsigned short)(um >> 16);
  l = (unsigned short)(ul >> 16);
}

// ---- scores via bf16x3 MFMA + per-tile row-softmax partials (max, sumexp) ----
__global__ __launch_bounds__(TPB, 2)
void k_scores_mfma(const float* __restrict__ Q, const float* __restrict__ K,
                   float* __restrict__ S, float* __restrict__ pm,
                   float* __restrict__ ps) {
  int blk = blockIdx.x;            // btc*16 + rt*4 + ct
  int btc = blk >> 4, rt = (blk >> 2) & 3, ct = blk & 3;
  const float* Qb = Q + (long)btc * NN * DD + (long)rt * 128 * DD;
  const float* Kb = K + (long)btc * NN * DD + (long)ct * 128 * DD;
  float* Sb = S + (long)btc * NN * NN + (long)rt * 128 * NN + ct * 128;

  __shared__ unsigned short Qh[128][40], Qm[128][40], Ql[128][40];
  __shared__ unsigned short Kh[128][40], Km[128][40], Kl[128][40];

  const int tid = threadIdx.x;
  const int lane = tid & 63;
  const int wave = tid >> 6;
  const int frow = lane & 15;
  const int kgrp = lane >> 4;
  const int rbase = wave * 32;

  floatx4 acc[2][8];
  #pragma unroll
  for (int i = 0; i < 2; ++i)
    #pragma unroll
    for (int j = 0; j < 8; ++j)
      acc[i][j] = (floatx4){0.f, 0.f, 0.f, 0.f};

  for (int k0 = 0; k0 < 128; k0 += 32) {
    __syncthreads();
    #pragma unroll
    for (int u = tid; u < 2048; u += TPB) {
      int mat = u >> 10, rem = u & 1023;
      int row = rem >> 3, k4 = (rem & 7) << 2;
      const float* src = (mat ? Kb : Qb) + (long)row * DD + k0 + k4;
      float4 v = *(const float4*)src;
      unsigned short h0, m0, l0, h1, m1, l1, h2, m2, l2, h3, m3, l3;
      split3(v.x, h0, m0, l0); split3(v.y, h1, m1, l1);
      split3(v.z, h2, m2, l2); split3(v.w, h3, m3, l3);
      if (mat == 0) {
        Qh[row][k4] = h0; Qh[row][k4+1] = h1; Qh[row][k4+2] = h2; Qh[row][k4+3] = h3;
        Qm[row][k4] = m0; Qm[row][k4+1] = m1; Qm[row][k4+2] = m2; Qm[row][k4+3] = m3;
        Ql[row][k4] = l0; Ql[row][k4+1] = l1; Ql[row][k4+2] = l2; Ql[row][k4+3] = l3;
      } else {
        Kh[row][k4] = h0; Kh[row][k4+1] = h1; Kh[row][k4+2] = h2; Kh[row][k4+3] = h3;
        Km[row][k4] = m0; Km[row][k4+1] = m1; Km[row][k4+2] = m2; Km[row][k4+3] = m3;
        Kl[row][k4] = l0; Kl[row][k4+1] = l1; Kl[row][k4+2] = l2; Kl[row][k4+3] = l3;
      }
    }
    __syncthreads();

    const int mk = kgrp * 8;
    bf16x8 aH0 = *(const bf16x8*)&Qh[rbase + frow][mk];
    bf16x8 aH1 = *(const bf16x8*)&Qh[rbase + 16 + frow][mk];
    bf16x8 aM0 = *(const bf16x8*)&Qm[rbase + frow][mk];
    bf16x8 aM1 = *(const bf16x8*)&Qm[rbase + 16 + frow][mk];
    bf16x8 aL0 = *(const bf16x8*)&Ql[rbase + frow][mk];
    bf16x8 aL1 = *(const bf16x8*)&Ql[rbase + 16 + frow][mk];
    #pragma unroll
    for (int j = 0; j < 8; ++j) {
      bf16x8 bH = *(const bf16x8*)&Kh[j * 16 + frow][mk];
      bf16x8 bM = *(const bf16x8*)&Km[j * 16 + frow][mk];
      bf16x8 bL = *(const bf16x8*)&Kl[j * 16 + frow][mk];
      acc[0][j] = __builtin_amdgcn_mfma_f32_16x16x32_bf16(aM0, bM, acc[0][j], 0, 0, 0);
      acc[1][j] = __builtin_amdgcn_mfma_f32_16x16x32_bf16(aM1, bM, acc[1][j], 0, 0, 0);
      acc[0][j] = __builtin_amdgcn_mfma_f32_16x16x32_bf16(aH0, bL, acc[0][j], 0, 0, 0);
      acc[1][j] = __builtin_amdgcn_mfma_f32_16x16x32_bf16(aH1, bL, acc[1][j], 0, 0, 0);
      acc[0][j] = __builtin_amdgcn_mfma_f32_16x16x32_bf16(aL0, bH, acc[0][j], 0, 0, 0);
      acc[1][j] = __builtin_amdgcn_mfma_f32_16x16x32_bf16(aL1, bH, acc[1][j], 0, 0, 0);
      acc[0][j] = __builtin_amdgcn_mfma_f32_16x16x32_bf16(aH0, bM, acc[0][j], 0, 0, 0);
      acc[1][j] = __builtin_amdgcn_mfma_f32_16x16x32_bf16(aH1, bM, acc[1][j], 0, 0, 0);
      acc[0][j] = __builtin_amdgcn_mfma_f32_16x16x32_bf16(aM0, bH, acc[0][j], 0, 0, 0);
      acc[1][j] = __builtin_amdgcn_mfma_f32_16x16x32_bf16(aM1, bH, acc[1][j], 0, 0, 0);
      acc[0][j] = __builtin_amdgcn_mfma_f32_16x16x32_bf16(aH0, bH, acc[0][j], 0, 0, 0);
      acc[1][j] = __builtin_amdgcn_mfma_f32_16x16x32_bf16(aH1, bH, acc[1][j], 0, 0, 0);
    }
  }
  // store S
  #pragma unroll
  for (int i = 0; i < 2; ++i)
    #pragma unroll
    for (int j = 0; j < 8; ++j)
      #pragma unroll
      for (int r = 0; r < 4; ++r)
        Sb[(long)(rbase + i * 16 + kgrp * 4 + r) * NN + j * 16 + frow] =
            acc[i][j][r] * SCALE;
  // per-row partial (max, sumexp) over this 128-col tile; 16-lane row group reduce
  #pragma unroll
  for (int i = 0; i < 2; ++i)
    #pragma unroll
    for (int r = 0; r < 4; ++r) {
      float mx = -3.4e38f;
      #pragma unroll
      for (int j = 0; j < 8; ++j) mx = fmaxf(mx, acc[i][j][r] * SCALE);
      #pragma unroll
      for (int d = 1; d < 16; d <<= 1) mx = fmaxf(mx, __shfl_xor(mx, d));
      float se = 0.f;
      #pragma unroll
      for (int j = 0; j < 8; ++j) se += __expf(acc[i][j][r] * SCALE - mx);
      #pragma unroll
      for (int d = 1; d < 16; d <<= 1) se += __shfl_xor(se, d);
      if (frow == 0) {
        int row = rbase + i * 16 + kgrp * 4 + r;
        long pidx = ((long)btc * 4 + ct) * NN + rt * 128 + row;
        pm[pidx] = mx; ps[pidx] = se;
      }
    }
}

// ---------------- combine 4 per-tile partials -> lse ----------------
__global__ void k_lse_combine(const float* __restrict__ pm, const float* __restrict__ ps,
                              float* __restrict__ lse, int total) {
  int idx = blockIdx.x * TPB + threadIdx.x;   // btc*512 + n
  if (idx >= total) return;
  int btc = idx >> 9, n = idx & 511;
  float mv[4], sv[4];
  float M = -3.4e38f;
  #pragma unroll
  for (int ct = 0; ct < 4; ++ct) {
    long p = ((long)btc * 4 + ct) * NN + n;
    mv[ct] = pm[p]; sv[ct] = ps[p];
    M = fmaxf(M, mv[ct]);
  }
  float tot = 0.f;
  #pragma unroll
  for (int ct = 0; ct < 4; ++ct) tot += sv[ct] * expf(mv[ct] - M);
  lse[idx] = M + logf(tot);
}

// ---- PV via fp16 MFMA + fused column argmax ----
// QBLK=64 rows/block (grid CH*8). v = S - lse < 0 always; key = ~bits(v) is
// order-isomorphic to fp32 compare; pack (key<<32)|(511-n) => atomicMax gives
// max v with first-index (smallest n) tie-break, matching sequential first-max.
__global__ __launch_bounds__(TPB, 3)
void k_pv_f16(const float* __restrict__ S, const float* __restrict__ lse,
              const float* __restrict__ V, float* __restrict__ att,
              unsigned long long* __restrict__ cpk) {
  int btc = blockIdx.x >> 3, nt = blockIdx.x & 7;
  const int n0 = nt * 64;
  const float* Sb = S + (long)btc * NN * NN + (long)n0 * NN;
  const float* lb = lse + btc * NN + n0;
  const float* Vb = V + (long)btc * NN * DD;
  float* attb = att + ((long)btc * NN + n0) * DD;
  unsigned long long* cpb = cpk + (long)btc * NN;

  __shared__ _Float16 Ph[64][72];            // P (fp16) [n][m]
  __shared__ _Float16 Vt[128][72];           // V^T swizzled [d][m ^ swz(d)]
  __shared__ float P32[64][65];              // v = S - lse (fp32, argmax keys)
  __shared__ unsigned long long colmax[64];

  const int tid = threadIdx.x;
  const int lane = tid & 63;
  const int wave = tid >> 6;
  const int frow = lane & 15;
  const int kgrp = lane >> 4;
  const int wr = wave * 16;                  // wave's 16 rows
  const int c = tid & 63, g = tid >> 6;      // argmax scan: col, row-group

  floatx4 acc[8];
  #pragma unroll
  for (int j = 0; j < 8; ++j) acc[j] = (floatx4){0.f, 0.f, 0.f, 0.f};

  for (int m0 = 0; m0 < NN; m0 += 64) {
    __syncthreads();                         // prev MFMA reads + prev atomics done
    if (tid < 64) {
      if (m0 > 0) atomicMax(&cpb[m0 - 64 + tid], colmax[tid]);
      colmax[tid] = 0ull;
    }
    // stage P rows (v in fp32 + exp in fp16)
    for (int u = tid; u < 64 * 16; u += TPB) {
      int n = u >> 4, m4 = (u & 15) << 2;
      float l = lb[n];
      float4 s4 = *(const float4*)(Sb + (long)n * NN + m0 + m4);
      float v0 = s4.x - l, v1 = s4.y - l, v2 = s4.z - l, v3 = s4.w - l;
      P32[n][m4 + 0] = v0; P32[n][m4 + 1] = v1;
      P32[n][m4 + 2] = v2; P32[n][m4 + 3] = v3;
      Ph[n][m4 + 0] = (_Float16)__expf(v0);
      Ph[n][m4 + 1] = (_Float16)__expf(v1);
      Ph[n][m4 + 2] = (_Float16)__expf(v2);
      Ph[n][m4 + 3] = (_Float16)__expf(v3);
    }
    // stage V^T with XOR swizzle (write 4-way instead of 16-way conflicts)
    for (int u = tid; u < 2048; u += TPB) {
      int d4 = (u & 31) << 2, m = u >> 5;
      int mc = m ^ (((d4 >> 2) & 7) << 3);
      float4 v4 = *(const float4*)(Vb + (long)(m0 + m) * DD + d4);
      Vt[d4 + 0][mc] = (_Float16)v4.x;
      Vt[d4 + 1][mc] = (_Float16)v4.y;
      Vt[d4 + 2][mc] = (_Float16)v4.z;
      Vt[d4 + 3][mc] = (_Float16)v4.w;
    }
    __syncthreads();
    // column argmax over this block's 64 rows (register scan + 1 LDS atomic)
    {
      float best = -3.4e38f;
      int bi = g * 16;
      #pragma unroll
      for (int t = 0; t < 16; ++t) {
        float v = P32[g * 16 + t][c];
        if (v > best) { best = v; bi = g * 16 + t; }
      }
      unsigned key = ~__float_as_uint(best);
      unsigned long long pk =
          ((unsigned long long)key << 32) | (unsigned)(NN - 1 - (n0 + bi));
      atomicMax(&colmax[c], pk);
    }
    // MFMA
    #pragma unroll
    for (int ks = 0; ks < 2; ++ks) {
      const int mk = ks * 32 + kgrp * 8;
      half8 a = *(const half8*)&Ph[wr + frow][mk];
      #pragma unroll
      for (int j = 0; j < 8; ++j) {
        const int d = j * 16 + frow;
        const int swz = ((d >> 2) & 7) << 3;
        half8 b = *(const half8*)&Vt[d][mk ^ swz];
        acc[j] = __builtin_amdgcn_mfma_f32_16x16x32_f16(a, b, acc[j], 0, 0, 0);
      }
    }
  }
  __syncthreads();
  if (tid < 64) atomicMax(&cpb[NN - 64 + tid], colmax[tid]);
  // write attended
  #pragma unroll
  for (int j = 0; j < 8; ++j)
    #pragma unroll
    for (int r = 0; r < 4; ++r)
      attb[(long)(wr + kgrp * 4 + r) * DD + j * 16 + frow] = acc[j][r];
}

// ---- gather + Wo + residual + LN + FFN, fp16 MFMA (cp unpacked inline) ----
__global__ __launch_bounds__(TPB, 2)
void k_wo_ln_ffn(const float* __restrict__ att, const unsigned long long* __restrict__ cpk,
                 const float* __restrict__ Wo, const float* __restrict__ bo,
                 const float* __restrict__ xr,
                 const float* __restrict__ W1, const float* __restrict__ b1,
                 const float* __restrict__ W2, const float* __restrict__ b2,
                 float* __restrict__ out) {
  const int blk = blockIdx.x, btc = blk >> 2, rt = blk & 3;
  const int n0 = rt * 128;
  const long g0 = (long)btc * NN + n0;
  const float* attb = att + (long)btc * NN * DD;
  const unsigned long long* cpb = cpk + g0;

  __shared__ _Float16 At[128][136];
  __shared__ _Float16 Bt[128][136];

  const int tid = threadIdx.x;
  const int lane = tid & 63;
  const int wave = tid >> 6;
  const int frow = lane & 15;
  const int kgrp = lane >> 4;
  const int rbase = wave * 32;

  auto stage_wT = [&](const float* __restrict__ W) {
    for (int u = tid; u < 128 * 32; u += TPB) {
      int k = u >> 5, c4 = (u & 31) << 2;
      float4 v4 = *(const float4*)(W + (long)k * DD + c4);
      Bt[c4 + 0][k] = (_Float16)v4.x; Bt[c4 + 1][k] = (_Float16)v4.y;
      Bt[c4 + 2][k] = (_Float16)v4.z; Bt[c4 + 3][k] = (_Float16)v4.w;
    }
  };

  floatx4 acc[2][8];
  auto zero_acc = [&]() {
    #pragma unroll
    for (int i = 0; i < 2; ++i)
      #pragma unroll
      for (int j = 0; j < 8; ++j)
        acc[i][j] = (floatx4){0.f, 0.f, 0.f, 0.f};
  };
  auto mfma_tile = [&]() {
    #pragma unroll
    for (int ks = 0; ks < 4; ++ks) {
      const int mk = ks * 32 + kgrp * 8;
      half8 a0 = *(const half8*)&At[rbase + frow][mk];
      half8 a1 = *(const half8*)&At[rbase + 16 + frow][mk];
      #pragma unroll
      for (int j = 0; j < 8; ++j) {
        half8 b = *(const half8*)&Bt[j * 16 + frow][mk];
        acc[0][j] = __builtin_amdgcn_mfma_f32_16x16x32_f16(a0, b, acc[0][j], 0, 0, 0);
        acc[1][j] = __builtin_amdgcn_mfma_f32_16x16x32_f16(a1, b, acc[1][j], 0, 0, 0);
      }
    }
  };

  // Phase A: gathered attended @ Wo
  for (int u = tid; u < 128 * 32; u += TPB) {
    int r = u >> 5, k4 = (u & 31) << 2;
    int src = NN - 1 - (int)(unsigned)(cpb[r] & 0xFFFFFFFFull);
    float4 v4 = *(const float4*)(attb + (long)src * DD + k4);
    At[r][k4 + 0] = (_Float16)v4.x; At[r][k4 + 1] = (_Float16)v4.y;
    At[r][k4 + 2] = (_Float16)v4.z; At[r][k4 + 3] = (_Float16)v4.w;
  }
  stage_wT(Wo);
  __syncthreads();
  zero_acc();
  mfma_tile();
  __syncthreads();

  // bias + residual + LayerNorm in registers
  float v[2][8][4];
  #pragma unroll
  for (int i = 0; i < 2; ++i)
    #pragma unroll
    for (int j = 0; j < 8; ++j) {
      const int col = j * 16 + frow;
      const float bb = bo[col];
      #pragma unroll
      for (int r = 0; r < 4; ++r) {
        const long grow = g0 + rbase + i * 16 + kgrp * 4 + r;
        v[i][j][r] = acc[i][j][r] + bb + xr[grow * DD + col];
      }
    }
  #pragma unroll
  for (int i = 0; i < 2; ++i)
    #pragma unroll
    for (int r = 0; r < 4; ++r) {
      float s = 0.f, ss = 0.f;
      #pragma unroll
      for (int j = 0; j < 8; ++j) { float t = v[i][j][r]; s += t; ss += t * t; }
      #pragma unroll
      for (int d = 1; d < 16; d <<= 1) { s += __shfl_xor(s, d); ss += __shfl_xor(ss, d); }
      float mu = s * (1.f / 128.f);
      float var = ss * (1.f / 128.f) - mu * mu;
      float rs = rsqrtf(var + LNEPS);
      #pragma unroll
      for (int j = 0; j < 8; ++j) v[i][j][r] = (v[i][j][r] - mu) * rs;
    }
  #pragma unroll
  for (int i = 0; i < 2; ++i)
    #pragma unroll
    for (int j = 0; j < 8; ++j)
      #pragma unroll
      for (int r = 0; r < 4; ++r)
        At[rbase + i * 16 + kgrp * 4 + r][j * 16 + frow] = (_Float16)v[i][j][r];
  stage_wT(W1);
  __syncthreads();

  // Phase B: H = relu(LN @ W1 + b1)
  zero_acc();
  mfma_tile();
  __syncthreads();
  #pragma unroll
  for (int i = 0; i < 2; ++i)
    #pragma unroll
    for (int j = 0; j < 8; ++j) {
      const int col = j * 16 + frow;
      const float bb = b1[col];
      #pragma unroll
      for (int r = 0; r < 4; ++r)
        At[rbase + i * 16 + kgrp * 4 + r][col] = (_Float16)fmaxf(acc[i][j][r] + bb, 0.f);
    }
  stage_wT(W2);
  __syncthreads();

  // Phase C: out = H @ W2 + b2
  zero_acc();
  mfma_tile();
  #pragma unroll
  for (int i = 0; i < 2; ++i)
    #pragma unroll
    for (int j = 0; j < 8; ++j) {
      const int col = j * 16 + frow;
      const float bb = b2[col];
      #pragma unroll
      for (int r = 0; r < 4; ++r) {
        const long grow = g0 + rbase + i * 16 + kgrp * 4 + r;
        out[grow * DD + col] = acc[i][j][r] + bb;
      }
    }
}

// ---------------- launch ----------------
extern "C" void kernel_launch(void* const* d_in, const int* in_sizes, int n_in,
                              void* d_out, int out_size, void* d_ws, size_t ws_size,
                              hipStream_t stream) {
  const float* x    = (const float*)d_in[0];
  const float* adj  = (const float*)d_in[1];
  const float* Wq   = (const float*)d_in[2];
  const float* bq   = (const float*)d_in[3];
  const float* Wk   = (const float*)d_in[4];
  const float* bk   = (const float*)d_in[5];
  const float* Wv   = (const float*)d_in[6];
  const float* bv   = (const float*)d_in[7];
  const float* Wo   = (const float*)d_in[8];
  const float* bo   = (const float*)d_in[9];
  const float* W1   = (const float*)d_in[10];
  const float* b1   = (const float*)d_in[11];
  const float* W2   = (const float*)d_in[12];
  const float* b2   = (const float*)d_in[13];
  float* out = (float*)d_out;
  (void)in_sizes; (void)n_in; (void)out_size;

  // per-bt: xr/Q/K/V/att (0.25 MiB each) + S (1 MiB) + lse + pm/ps + cpk
  const size_t BT_ROWBYTES = (size_t)NN * DD * 4;                 // 262144
  const size_t per_bt = 5 * BT_ROWBYTES + (size_t)NN * NN * 4 + (size_t)NN * 4
                      + 2 * 4 * (size_t)NN * 4 + (size_t)NN * 8;
  static const int divs[] = {192, 96, 64, 48, 32, 24, 16, 12, 8, 6, 4, 3, 2, 1};
  int CH = 1;
  for (int i = 0; i < 14; ++i) {
    if ((size_t)divs[i] * per_bt + 8192 <= ws_size) { CH = divs[i]; break; }
  }

  char* ws = (char*)d_ws;
  size_t off = 0;
  auto alloc = [&](size_t bytes) -> void* {
    void* p = ws + off;
    off += (bytes + 255) & ~(size_t)255;
    return p;
  };
  float* xrc  = (float*)alloc((size_t)CH * BT_ROWBYTES);
  float* Qc   = (float*)alloc((size_t)CH * BT_ROWBYTES);
  float* Kc   = (float*)alloc((size_t)CH * BT_ROWBYTES);
  float* Vc   = (float*)alloc((size_t)CH * BT_ROWBYTES);
  float* attc = (float*)alloc((size_t)CH * BT_ROWBYTES);
  float* Sc   = (float*)alloc((size_t)CH * NN * NN * 4);
  float* lsec = (float*)alloc((size_t)CH * NN * 4);
  float* pmc  = (float*)alloc((size_t)CH * 4 * NN * 4);
  float* psc  = (float*)alloc((size_t)CH * 4 * NN * 4);
  unsigned long long* cpkc = (unsigned long long*)alloc((size_t)CH * NN * 8);

  for (int c0 = 0; c0 < BTT; c0 += CH) {
    const size_t elemoff = (size_t)c0 * NN * DD;
    const float* xb  = x + elemoff;
    const float* ab  = adj + elemoff;
    float* outb = out + elemoff;
    int n4c = CH * NN * DD / 4;

    k_add<<<n4c / TPB, TPB, 0, stream>>>(xb, ab, xrc, n4c);

    k_gemm_bias<<<CH * 4, TPB, 0, stream>>>(xrc, Wq, bq, Qc);
    k_gemm_bias<<<CH * 4, TPB, 0, stream>>>(xrc, Wk, bk, Kc);
    k_gemm_bias_f16<<<CH * 4, TPB, 0, stream>>>(xrc, Wv, bv, Vc);

    k_scores_mfma<<<CH * 16, TPB, 0, stream>>>(Qc, Kc, Sc, pmc, psc);
    k_lse_combine<<<CH * 2, TPB, 0, stream>>>(pmc, psc, lsec, CH * NN);
    hipMemsetAsync(cpkc, 0, (size_t)CH * NN * 8, stream);
    k_pv_f16<<<CH * 8, TPB, 0, stream>>>(Sc, lsec, Vc, attc, cpkc);

    k_wo_ln_ffn<<<CH * 4, TPB, 0, stream>>>(attc, cpkc, Wo, bo, xrc,
                                            W1, b1, W2, b2, outb);
  }
}